// Round 17
// baseline (855.536 us; speedup 1.0000x reference)
//
#include <hip/hip_runtime.h>
#include <hip/hip_cooperative_groups.h>

typedef unsigned short u16;
typedef __attribute__((ext_vector_type(8))) unsigned short us8;
typedef __attribute__((ext_vector_type(8))) __bf16 bf16x8;
typedef __attribute__((ext_vector_type(4))) float f32x4;

#define B_ 32
#define T_ 64
#define V_ 32000
#define E_ 300
#define H_ 512
#define G4_ 2048   // 4*H
#define NBLK_ 32   // scan blocks
#define NWRK_ 223  // gemm worker blocks (1 master + workers + scan = 256)
#define NT_TILES 250
#define NM_TILES 16

__device__ __forceinline__ u16 f2b(float f){
  unsigned int x = __builtin_bit_cast(unsigned int, f);
  unsigned int r = (x + 0x7FFFu + ((x >> 16) & 1u)) >> 16;
  return (u16)r;
}
__device__ __forceinline__ float sigm(float x){ return 1.0f/(1.0f+expf(-x)); }

__device__ __forceinline__ void gload16(const u16* g, u16* l){
  __builtin_amdgcn_global_load_lds(
      (const __attribute__((address_space(1))) void*)g,
      (__attribute__((address_space(3))) void*)l, 16, 0, 0);
}

// ---------------------------------------------------------------------------
// Kernel 1: h0 = init_h[0] @ Wh^T + bh ; c0 = init_c[0] @ Wc^T + bc   (f32)
// Also zeroes the 32 scan flags + the aggregated gate cell every call.
// ---------------------------------------------------------------------------
__global__ __launch_bounds__(256) void k_init(
    const float* __restrict__ init_h, const float* __restrict__ init_c,
    const float* __restrict__ Wh, const float* __restrict__ bh,
    const float* __restrict__ Wc, const float* __restrict__ bc,
    float* __restrict__ h0out, float* __restrict__ c0out,
    unsigned int* __restrict__ flag, unsigned int* __restrict__ gate)
{
  if (blockIdx.x == 0){
    flag[threadIdx.x] = 0u; flag[threadIdx.x + 256] = 0u;
    if (threadIdx.x == 0) gate[0] = 0u;
  }
  int idx = blockIdx.x*blockDim.x + threadIdx.x;    // 0..32767
  int sel = idx >> 14;                              // 0: h, 1: c
  int r = idx & 16383;
  int b = r >> 9, j = r & 511;
  const float* x = (sel ? init_c : init_h) + b*H_;
  const float* w = (sel ? Wc : Wh) + (size_t)j*H_;
  const float* bias = sel ? bc : bh;
  float acc = 0.f;
  for (int k = 0; k < H_; k += 8){
    f32x4 x0 = *(const f32x4*)(x + k), x1 = *(const f32x4*)(x + k + 4);
    f32x4 w0 = *(const f32x4*)(w + k), w1 = *(const f32x4*)(w + k + 4);
    acc += x0[0]*w0[0] + x0[1]*w0[1] + x0[2]*w0[2] + x0[3]*w0[3];
    acc += x1[0]*w1[0] + x1[1]*w1[1] + x1[2]*w1[2] + x1[3]*w1[3];
  }
  acc += bias[j];
  (sel ? c0out : h0out)[b*H_ + j] = acc;
}

// ---------------------------------------------------------------------------
// Kernel 1b: W_logit f32 -> bf16 prepass (16.384M elems, 8/thread, exact grid)
// ---------------------------------------------------------------------------
__global__ __launch_bounds__(256) void k_cvt(
    const float* __restrict__ W, u16* __restrict__ W16)
{
  size_t i = ((size_t)blockIdx.x*256 + threadIdx.x)*8;
  f32x4 a = *(const f32x4*)(W + i);
  f32x4 b = *(const f32x4*)(W + i + 4);
  us8 u;
  u[0]=f2b(a[0]); u[1]=f2b(a[1]); u[2]=f2b(a[2]); u[3]=f2b(a[3]);
  u[4]=f2b(b[0]); u[5]=f2b(b[1]); u[6]=f2b(b[2]); u[7]=f2b(b[3]);
  *(us8*)(W16 + i) = u;
}

// ---------------------------------------------------------------------------
// Kernel 2: xg[t][b][g] = emb[token(b,t)] . W_ih[g] + b_ih[g] + b_hh[g]  (f32)
// MFMA GEMM, M=2048 (rows r=t*32+b gathered from embedding), N=2048, K=300.
// ---------------------------------------------------------------------------
__global__ __launch_bounds__(256) void k_xgates(
    const float* __restrict__ emb, const float* __restrict__ Wih,
    const int* __restrict__ trg, const float* __restrict__ bih,
    const float* __restrict__ bhh, float* __restrict__ xg)
{
  __shared__ u16 As[128][40];   // +8 pad: row stride 80B -> conflict-free b128
  __shared__ u16 Bs[128][40];
  const int bn0 = blockIdx.x*128, bm0 = blockIdx.y*128;
  const int tid = threadIdx.x;
  const int w = tid>>6, lane = tid&63;
  const int wr = w>>1, wc = w&1, lr = lane&15, lk = lane>>4;
  const int srow = tid>>1, half = tid&1;
  const int R = bm0 + srow;
  const int tt = R>>5, bb = R&31;
  const int token = trg[bb*T_ + tt];
  const float* arow = emb + (size_t)token*E_;
  const float* brow = Wih + (size_t)(bn0+srow)*E_;
  f32x4 acc[4][4] = {};
  for (int k0 = 0; k0 < E_; k0 += 32){
    int cbase = k0 + half*16;
    if (k0 + 32 <= E_){
      f32x4 a0=*(const f32x4*)(arow+cbase),    a1=*(const f32x4*)(arow+cbase+4);
      f32x4 a2=*(const f32x4*)(arow+cbase+8),  a3=*(const f32x4*)(arow+cbase+12);
      f32x4 b0=*(const f32x4*)(brow+cbase),    b1=*(const f32x4*)(brow+cbase+4);
      f32x4 b2=*(const f32x4*)(brow+cbase+8),  b3=*(const f32x4*)(brow+cbase+12);
      us8 ua, ub;
      ua[0]=f2b(a0[0]); ua[1]=f2b(a0[1]); ua[2]=f2b(a0[2]); ua[3]=f2b(a0[3]);
      ua[4]=f2b(a1[0]); ua[5]=f2b(a1[1]); ua[6]=f2b(a1[2]); ua[7]=f2b(a1[3]);
      ub[0]=f2b(a2[0]); ub[1]=f2b(a2[1]); ub[2]=f2b(a2[2]); ub[3]=f2b(a2[3]);
      ub[4]=f2b(a3[0]); ub[5]=f2b(a3[1]); ub[6]=f2b(a3[2]); ub[7]=f2b(a3[3]);
      *(us8*)&As[srow][half*16]   = ua;
      *(us8*)&As[srow][half*16+8] = ub;
      us8 va, vb;
      va[0]=f2b(b0[0]); va[1]=f2b(b0[1]); va[2]=f2b(b0[2]); va[3]=f2b(b0[3]);
      va[4]=f2b(b1[0]); va[5]=f2b(b1[1]); va[6]=f2b(b1[2]); va[7]=f2b(b1[3]);
      vb[0]=f2b(b2[0]); vb[1]=f2b(b2[1]); vb[2]=f2b(b2[2]); vb[3]=f2b(b2[3]);
      vb[4]=f2b(b3[0]); vb[5]=f2b(b3[1]); vb[6]=f2b(b3[2]); vb[7]=f2b(b3[3]);
      *(us8*)&Bs[srow][half*16]   = va;
      *(us8*)&Bs[srow][half*16+8] = vb;
    } else {
      for (int i = 0; i < 16; i++){
        int c = cbase + i;
        As[srow][half*16+i] = (c < E_) ? f2b(arow[c]) : (u16)0;
        Bs[srow][half*16+i] = (c < E_) ? f2b(brow[c]) : (u16)0;
      }
    }
    __syncthreads();
    bf16x8 af[4], bfr[4];
    #pragma unroll
    for (int m = 0; m < 4; m++) af[m] = *(const bf16x8*)&As[wr*64 + m*16 + lr][lk*8];
    #pragma unroll
    for (int n = 0; n < 4; n++) bfr[n] = *(const bf16x8*)&Bs[wc*64 + n*16 + lr][lk*8];
    #pragma unroll
    for (int m = 0; m < 4; m++)
      #pragma unroll
      for (int n = 0; n < 4; n++)
        acc[m][n] = __builtin_amdgcn_mfma_f32_16x16x32_bf16(af[m], bfr[n], acc[m][n], 0, 0, 0);
    __syncthreads();
  }
  #pragma unroll
  for (int n = 0; n < 4; n++){
    int col = bn0 + wc*64 + n*16 + lr;
    float bv = bih[col] + bhh[col];
    #pragma unroll
    for (int m = 0; m < 4; m++){
      #pragma unroll
      for (int i = 0; i < 4; i++){
        int row = bm0 + wr*64 + m*16 + lk*4 + i;
        xg[(size_t)row*G4_ + col] = acc[m][n][i] + bv;
      }
    }
  }
}

// ---------------------------------------------------------------------------
// Mega kernel (cooperative, 256 blocks x 512 thr):
//   block  [0,32):  LSTM scan (round-9 structure) + final release flag=65.
//   block  32:      GATE MASTER: polls the 32 scan flags, publishes the
//                   aggregated group level (1..4) to ONE gate line. Workers
//                   no longer hammer the 32 flag lines the scan releases to.
//   blocks [33,256): 223 GEMM workers. 4 gate groups (q: mt in [4q,4q+4),
//                   want = 16q+17, final 65 -- same A_t certification).
//                   Within a group: NT-OUTER, MT-INNER -- each W panel is
//                   loaded once and reused for 4 mt rows back-to-back
//                   (per-XCD W set ~4MB, fits L2; W fetched ~once per group).
// LDS: manual union, 41472 B (scan: 33280+8192; gemm: 2x8192).
// ---------------------------------------------------------------------------
__global__ __launch_bounds__(512, 4) void k_mega(
    const float* __restrict__ Whh, const float* __restrict__ xg,
    const float* __restrict__ h0, const float* __restrict__ c0,
    u16* __restrict__ h_g, u16* __restrict__ A_buf,
    unsigned int* __restrict__ flag, unsigned int* __restrict__ gate,
    const u16* __restrict__ W16, const float* __restrict__ bias,
    float* __restrict__ out)
{
  __shared__ __align__(16) char smem[41472];
  const int tid = threadIdx.x;

  if (blockIdx.x < NBLK_){
    // ======================= SCAN PATH (round-9 verbatim) ==================
    u16 (*hl)[520] = (u16(*)[520])smem;
    float (*gb)[32][16] = (float(*)[32][16])(smem + 33280);
    const int bj = blockIdx.x;
    const int wv = tid >> 6, lane = tid & 63;
    const int g = wv >> 1, m = wv & 1;
    const int lr = lane & 15, lk = lane >> 4;

    bf16x8 bw[16];
    {
      const float* wsrc = Whh + (size_t)(g*H_ + bj*16 + lr)*H_;
      #pragma unroll
      for (int ks = 0; ks < 16; ks++){
        f32x4 w0 = *(const f32x4*)(wsrc + ks*32 + lk*8);
        f32x4 w1 = *(const f32x4*)(wsrc + ks*32 + lk*8 + 4);
        us8 u;
        u[0]=f2b(w0[0]); u[1]=f2b(w0[1]); u[2]=f2b(w0[2]); u[3]=f2b(w0[3]);
        u[4]=f2b(w1[0]); u[5]=f2b(w1[1]); u[6]=f2b(w1[2]); u[7]=f2b(w1[3]);
        bw[ks] = __builtin_bit_cast(bf16x8, u);
      }
    }
    const int ub = tid >> 4, uj = tid & 15;
    float c_reg = c0[ub*H_ + bj*16 + uj];

    {
      int r = tid >> 4, seg = tid & 15;
      const float* src = h0 + r*H_ + seg*32;
      #pragma unroll
      for (int q = 0; q < 4; q++){
        f32x4 v0 = *(const f32x4*)(src + q*8);
        f32x4 v1 = *(const f32x4*)(src + q*8 + 4);
        us8 u;
        u[0]=f2b(v0[0]); u[1]=f2b(v0[1]); u[2]=f2b(v0[2]); u[3]=f2b(v0[3]);
        u[4]=f2b(v1[0]); u[5]=f2b(v1[1]); u[6]=f2b(v1[2]); u[7]=f2b(v1[3]);
        *(us8*)&hl[r][seg*32 + q*8] = u;
      }
    }
    __syncthreads();

    for (int t = 0; t < T_; t++){
      const float* xr = xg + (size_t)t*(B_*G4_) + ub*G4_ + bj*16 + uj;
      float x0 = xr[0*H_], x1 = xr[1*H_], x2 = xr[2*H_], x3 = xr[3*H_];

      f32x4 acc = {0.f, 0.f, 0.f, 0.f};
      #pragma unroll
      for (int ks = 0; ks < 16; ks++){
        bf16x8 a = *(const bf16x8*)&hl[m*16 + lr][ks*32 + lk*8];
        acc = __builtin_amdgcn_mfma_f32_16x16x32_bf16(a, bw[ks], acc, 0, 0, 0);
      }
      #pragma unroll
      for (int i = 0; i < 4; i++)
        gb[g][m*16 + lk*4 + i][lr] = acc[i];
      __syncthreads();

      float gi = sigm(gb[0][ub][uj] + x0);
      float gf = sigm(gb[1][ub][uj] + x1);
      float gg = tanhf(gb[2][ub][uj] + x2);
      float go = sigm(gb[3][ub][uj] + x3);
      c_reg = gf*c_reg + gi*gg;
      float h = go * tanhf(c_reg);
      int p = (t+1) & 1;
      h_g[p*(B_*H_) + bj*(B_*16) + tid] = f2b(h);

      __syncthreads();   // drains h_g stores (vmcnt0) before release
      if (t < T_-1 && tid == 0)
        __hip_atomic_store(&flag[bj*16], (unsigned)(t+1),
                           __ATOMIC_RELEASE, __HIP_MEMORY_SCOPE_AGENT);

      A_buf[(size_t)t*(B_*H_) + ub*H_ + bj*16 + uj] = f2b(tanhf(h));
      if (t == T_-1) break;

      if (tid < 64){
        unsigned want = (unsigned)(t+1), guard = 0;
        while (__hip_atomic_load(&flag[(tid&31)*16], __ATOMIC_ACQUIRE,
                                 __HIP_MEMORY_SCOPE_AGENT) < want
               && guard < (1u<<18)) { __builtin_amdgcn_s_sleep(1); ++guard; }
      }
      __syncthreads();

      {
        int r = tid >> 4, seg = tid & 15;
        const u16* hb = h_g + p*(B_*H_);
        const u16* p0 = hb + (seg*2)  *(B_*16) + r*16;
        const u16* p1 = hb + (seg*2+1)*(B_*16) + r*16;
        us8 v0 = *(const us8*)(p0);
        us8 v1 = *(const us8*)(p0 + 8);
        us8 v2 = *(const us8*)(p1);
        us8 v3 = *(const us8*)(p1 + 8);
        *(us8*)&hl[r][seg*32]      = v0;
        *(us8*)&hl[r][seg*32 + 8]  = v1;
        *(us8*)&hl[r][seg*32 + 16] = v2;
        *(us8*)&hl[r][seg*32 + 24] = v3;
      }
      __syncthreads();
    }
    // final publish: A of t=63 (and all prior) flushed by this release
    __syncthreads();   // drain last A_buf stores
    if (tid == 0)
      __hip_atomic_store(&flag[bj*16], 65u,
                         __ATOMIC_RELEASE, __HIP_MEMORY_SCOPE_AGENT);
  } else if (blockIdx.x == NBLK_){
    // ======================= GATE MASTER ==================================
    // One wave polls the 32 scan flags; publishes aggregated level 1..4.
    if (tid < 64){
      for (int q = 0; q < 4; q++){
        unsigned want = (q < 3) ? (unsigned)(16*q + 17) : 65u;
        unsigned guard = 0;
        for (;;){
          unsigned v = __hip_atomic_load(&flag[(tid&31)*16], __ATOMIC_ACQUIRE,
                                         __HIP_MEMORY_SCOPE_AGENT);
          if (__all(v >= want) || guard > (1u<<21)) break;
          __builtin_amdgcn_s_sleep(2); ++guard;
        }
        if (tid == 0)
          __hip_atomic_store(gate, (unsigned)(q+1),
                             __ATOMIC_RELEASE, __HIP_MEMORY_SCOPE_AGENT);
      }
    }
  } else {
    // =============== GEMM WORKERS (nt-outer within 4 gate groups) =========
    u16* As = (u16*)smem;
    u16* Bs = (u16*)(smem + 8192);
    const int w = tid>>6, lane = tid&63;
    const int wr = w & 1, wc = w >> 1;               // 2 x 4 wave grid
    const int lr = lane&15, lk = lane>>4;
    const int srow = w*16 + (lane>>2);               // 0..127
    const int cb   = ((lane&3)*16) ^ (((srow>>1)&3)<<4);
    u16* adst = &As[(w*16)*32];                      // wave rows [w*16,w*16+16)
    u16* bdst = &Bs[(w*16)*32];
    const int wid = (int)blockIdx.x - (NBLK_ + 1);   // 0..222

    for (int q = 0; q < 4; q++){
      if (tid == 0){
        unsigned guard = 0;
        while (__hip_atomic_load(gate, __ATOMIC_ACQUIRE,
                                 __HIP_MEMORY_SCOPE_AGENT) < (unsigned)(q+1)
               && guard < (1u<<21)) { __builtin_amdgcn_s_sleep(8); ++guard; }
      }
      __syncthreads();   // gate passed for whole block

      for (int nt = wid; nt < NT_TILES; nt += NWRK_){
        const int bn0 = nt*128;
        const u16* bpt = W16 + (size_t)(bn0+srow)*H_ + (cb>>1);
        for (int mtl = 0; mtl < 4; mtl++){          // W panel reused 4x (L2)
          const int bm0 = (q*4 + mtl)*128;
          const u16* apt = A_buf + (size_t)(bm0+srow)*H_ + (cb>>1);
          f32x4 acc[4][2] = {};
          for (int k0 = 0; k0 < H_; k0 += 32){
            gload16(apt + k0, adst);
            gload16(bpt + k0, bdst);
            __syncthreads();
            bf16x8 af[4], bfr[2];
            #pragma unroll
            for (int m = 0; m < 4; m++){
              int row = wr*64 + m*16 + lr;
              af[m] = *(const bf16x8*)((const char*)As + row*64 + ((lk*16) ^ (((row>>1)&3)<<4)));
            }
            #pragma unroll
            for (int n = 0; n < 2; n++){
              int row = wc*32 + n*16 + lr;
              bfr[n] = *(const bf16x8*)((const char*)Bs + row*64 + ((lk*16) ^ (((row>>1)&3)<<4)));
            }
            #pragma unroll
            for (int m = 0; m < 4; m++)
              #pragma unroll
              for (int n = 0; n < 2; n++)
                acc[m][n] = __builtin_amdgcn_mfma_f32_16x16x32_bf16(af[m], bfr[n], acc[m][n], 0, 0, 0);
            __syncthreads();
          }
          #pragma unroll
          for (int n = 0; n < 2; n++){
            int col = bn0 + wc*32 + n*16 + lr;
            float bv = bias[col];
            #pragma unroll
            for (int m = 0; m < 4; m++){
              #pragma unroll
              for (int i = 0; i < 4; i++){
                int row = bm0 + wr*64 + m*16 + lk*4 + i;
                int t = row>>5, b = row&31;
                __builtin_nontemporal_store(acc[m][n][i] + bv,
                    &out[(size_t)b*((size_t)T_*V_) + (size_t)t*V_ + col]);
              }
            }
          }
        }
      }
    }
  }
}

// ---------------------------------------------------------------------------
// Standalone fallback kernels (round-9 proven, 499us total path).
// ---------------------------------------------------------------------------
__global__ __launch_bounds__(512) void k_scan(
    const float* __restrict__ Whh, const float* __restrict__ xg,
    const float* __restrict__ h0, const float* __restrict__ c0,
    u16* __restrict__ h_g, u16* __restrict__ A_buf,
    unsigned int* __restrict__ flag)
{
  __shared__ u16 hl[32][520];
  __shared__ float gb[4][32][16];
  const int bj = blockIdx.x;
  const int tid = threadIdx.x;
  const int wv = tid >> 6, lane = tid & 63;
  const int g = wv >> 1, m = wv & 1;
  const int lr = lane & 15, lk = lane >> 4;
  bf16x8 bw[16];
  {
    const float* wsrc = Whh + (size_t)(g*H_ + bj*16 + lr)*H_;
    #pragma unroll
    for (int ks = 0; ks < 16; ks++){
      f32x4 w0 = *(const f32x4*)(wsrc + ks*32 + lk*8);
      f32x4 w1 = *(const f32x4*)(wsrc + ks*32 + lk*8 + 4);
      us8 u;
      u[0]=f2b(w0[0]); u[1]=f2b(w0[1]); u[2]=f2b(w0[2]); u[3]=f2b(w0[3]);
      u[4]=f2b(w1[0]); u[5]=f2b(w1[1]); u[6]=f2b(w1[2]); u[7]=f2b(w1[3]);
      bw[ks] = __builtin_bit_cast(bf16x8, u);
    }
  }
  const int ub = tid >> 4, uj = tid & 15;
  float c_reg = c0[ub*H_ + bj*16 + uj];
  {
    int r = tid >> 4, seg = tid & 15;
    const float* src = h0 + r*H_ + seg*32;
    #pragma unroll
    for (int q = 0; q < 4; q++){
      f32x4 v0 = *(const f32x4*)(src + q*8);
      f32x4 v1 = *(const f32x4*)(src + q*8 + 4);
      us8 u;
      u[0]=f2b(v0[0]); u[1]=f2b(v0[1]); u[2]=f2b(v0[2]); u[3]=f2b(v0[3]);
      u[4]=f2b(v1[0]); u[5]=f2b(v1[1]); u[6]=f2b(v1[2]); u[7]=f2b(v1[3]);
      *(us8*)&hl[r][seg*32 + q*8] = u;
    }
  }
  __syncthreads();
  for (int t = 0; t < T_; t++){
    const float* xr = xg + (size_t)t*(B_*G4_) + ub*G4_ + bj*16 + uj;
    float x0 = xr[0*H_], x1 = xr[1*H_], x2 = xr[2*H_], x3 = xr[3*H_];
    f32x4 acc = {0.f, 0.f, 0.f, 0.f};
    #pragma unroll
    for (int ks = 0; ks < 16; ks++){
      bf16x8 a = *(const bf16x8*)&hl[m*16 + lr][ks*32 + lk*8];
      acc = __builtin_amdgcn_mfma_f32_16x16x32_bf16(a, bw[ks], acc, 0, 0, 0);
    }
    #pragma unroll
    for (int i = 0; i < 4; i++)
      gb[g][m*16 + lk*4 + i][lr] = acc[i];
    __syncthreads();
    float gi = sigm(gb[0][ub][uj] + x0);
    float gf = sigm(gb[1][ub][uj] + x1);
    float gg = tanhf(gb[2][ub][uj] + x2);
    float go = sigm(gb[3][ub][uj] + x3);
    c_reg = gf*c_reg + gi*gg;
    float h = go * tanhf(c_reg);
    int p = (t+1) & 1;
    h_g[p*(B_*H_) + bj*(B_*16) + tid] = f2b(h);
    __syncthreads();
    if (t < T_-1 && tid == 0)
      __hip_atomic_store(&flag[bj*16], (unsigned)(t+1),
                         __ATOMIC_RELEASE, __HIP_MEMORY_SCOPE_AGENT);
    A_buf[(size_t)t*(B_*H_) + ub*H_ + bj*16 + uj] = f2b(tanhf(h));
    if (t == T_-1) break;
    if (tid < 64){
      unsigned want = (unsigned)(t+1), guard = 0;
      while (__hip_atomic_load(&flag[(tid&31)*16], __ATOMIC_ACQUIRE,
                               __HIP_MEMORY_SCOPE_AGENT) < want
             && guard < (1u<<18)) { __builtin_amdgcn_s_sleep(1); ++guard; }
    }
    __syncthreads();
    {
      int r = tid >> 4, seg = tid & 15;
      const u16* hb = h_g + p*(B_*H_);
      const u16* p0 = hb + (seg*2)  *(B_*16) + r*16;
      const u16* p1 = hb + (seg*2+1)*(B_*16) + r*16;
      us8 v0 = *(const us8*)(p0);
      us8 v1 = *(const us8*)(p0 + 8);
      us8 v2 = *(const us8*)(p1);
      us8 v3 = *(const us8*)(p1 + 8);
      *(us8*)&hl[r][seg*32]      = v0;
      *(us8*)&hl[r][seg*32 + 8]  = v1;
      *(us8*)&hl[r][seg*32 + 16] = v2;
      *(us8*)&hl[r][seg*32 + 24] = v3;
    }
    __syncthreads();
  }
}

__global__ __launch_bounds__(256) void k_logits16(
    const u16* __restrict__ A, const u16* __restrict__ W16,
    const float* __restrict__ bias, float* __restrict__ out)
{
  __shared__ u16 As[128*32];
  __shared__ u16 Bs[128*32];
  int bid = blockIdx.y*16 + blockIdx.x;      // 0..3999
  int nbid = (bid & 7)*500 + (bid >> 3);     // bijective (4000 = 8*500)
  const int bm0 = (nbid & 15)*128;
  const int bn0 = (nbid >> 4)*128;
  const int tid = threadIdx.x;
  const int w = tid>>6, lane = tid&63;
  const int wr = w>>1, wc = w&1, lr = lane&15, lk = lane>>4;
  const int srow = w*32 + (lane>>2);
  const int cb   = ((lane&3)*16) ^ (((srow>>1)&3)<<4);
  const u16* aptr = A   + (size_t)(bm0+srow)*H_ + (cb>>1);
  const u16* bptr = W16 + (size_t)(bn0+srow)*H_ + (cb>>1);
  u16* adst0 = &As[(w*32)*32];
  u16* adst1 = &As[(w*32+16)*32];
  u16* bdst0 = &Bs[(w*32)*32];
  u16* bdst1 = &Bs[(w*32+16)*32];
  f32x4 acc[4][4] = {};
  for (int k0 = 0; k0 < H_; k0 += 32){
    gload16(aptr + k0,          adst0);
    gload16(aptr + k0 + 16*H_,  adst1);
    gload16(bptr + k0,          bdst0);
    gload16(bptr + k0 + 16*H_,  bdst1);
    __syncthreads();
    bf16x8 af[4], bfr[4];
    #pragma unroll
    for (int m = 0; m < 4; m++){
      int row = wr*64 + m*16 + lr;
      af[m] = *(const bf16x8*)((const char*)As + row*64 + ((lk*16) ^ (((row>>1)&3)<<4)));
    }
    #pragma unroll
    for (int n = 0; n < 4; n++){
      int row = wc*64 + n*16 + lr;
      bfr[n] = *(const bf16x8*)((const char*)Bs + row*64 + ((lk*16) ^ (((row>>1)&3)<<4)));
    }
    #pragma unroll
    for (int m = 0; m < 4; m++)
      #pragma unroll
      for (int n = 0; n < 4; n++)
        acc[m][n] = __builtin_amdgcn_mfma_f32_16x16x32_bf16(af[m], bfr[n], acc[m][n], 0, 0, 0);
    __syncthreads();
  }
  #pragma unroll
  for (int n = 0; n < 4; n++){
    int col = bn0 + wc*64 + n*16 + lr;
    float bv = bias[col];
    #pragma unroll
    for (int m = 0; m < 4; m++){
      #pragma unroll
      for (int i = 0; i < 4; i++){
        int row = bm0 + wr*64 + m*16 + lk*4 + i;
        int t = row>>5, b = row&31;
        __builtin_nontemporal_store(acc[m][n][i] + bv,
            &out[(size_t)b*((size_t)T_*V_) + (size_t)t*V_ + col]);
      }
    }
  }
}

__global__ __launch_bounds__(256) void k_logits(
    const u16* __restrict__ A, const float* __restrict__ W,
    const float* __restrict__ bias, float* __restrict__ out)
{
  __shared__ u16 As[128][40];
  __shared__ u16 Bs[128][40];
  const int bm0 = blockIdx.x*128, bn0 = blockIdx.y*128;
  const int tid = threadIdx.x;
  const int w = tid>>6, lane = tid&63;
  const int wr = w>>1, wc = w&1, lr = lane&15, lk = lane>>4;
  const int srow = tid>>1, half = tid&1;
  const u16*   arow = A + (size_t)(bm0+srow)*H_;
  const float* brow = W + (size_t)(bn0+srow)*H_;
  f32x4 acc[4][4] = {};
  for (int k0 = 0; k0 < H_; k0 += 32){
    us8 a0 = *(const us8*)(arow + k0 + half*16);
    us8 a1 = *(const us8*)(arow + k0 + half*16 + 8);
    f32x4 b0 = *(const f32x4*)(brow + k0 + half*16);
    f32x4 b1 = *(const f32x4*)(brow + k0 + half*16 + 4);
    f32x4 b2 = *(const f32x4*)(brow + k0 + half*16 + 8);
    f32x4 b3 = *(const f32x4*)(brow + k0 + half*16 + 12);
    *(us8*)&As[srow][half*16]   = a0;
    *(us8*)&As[srow][half*16+8] = a1;
    us8 vb0, vb1;
    vb0[0]=f2b(b0[0]); vb0[1]=f2b(b0[1]); vb0[2]=f2b(b0[2]); vb0[3]=f2b(b0[3]);
    vb0[4]=f2b(b1[0]); vb0[5]=f2b(b1[1]); vb0[6]=f2b(b1[2]); vb0[7]=f2b(b1[3]);
    vb1[0]=f2b(b2[0]); vb1[1]=f2b(b2[1]); vb1[2]=f2b(b2[2]); vb1[3]=f2b(b2[3]);
    vb1[4]=f2b(b3[0]); vb1[5]=f2b(b3[1]); vb1[6]=f2b(b3[2]); vb1[7]=f2b(b3[3]);
    *(us8*)&Bs[srow][half*16]   = vb0;
    *(us8*)&Bs[srow][half*16+8] = vb1;
    __syncthreads();
    bf16x8 af[4], bfr[4];
    #pragma unroll
    for (int m = 0; m < 4; m++) af[m] = *(const bf16x8*)&As[wr*64 + m*16 + lr][lk*8];
    #pragma unroll
    for (int n = 0; n < 4; n++) bfr[n] = *(const bf16x8*)&Bs[wc*64 + n*16 + lr][lk*8];
    #pragma unroll
    for (int m = 0; m < 4; m++)
      #pragma unroll
      for (int n = 0; n < 4; n++)
        acc[m][n] = __builtin_amdgcn_mfma_f32_16x16x32_bf16(af[m], bfr[n], acc[m][n], 0, 0, 0);
    __syncthreads();
  }
  #pragma unroll
  for (int n = 0; n < 4; n++){
    int col = bn0 + wc*64 + n*16 + lr;
    float bv = bias[col];
    #pragma unroll
    for (int m = 0; m < 4; m++){
      #pragma unroll
      for (int i = 0; i < 4; i++){
        int row = bm0 + wr*64 + m*16 + lk*4 + i;
        int t = row>>5, b = row&31;
        out[(size_t)b*((size_t)T_*V_) + (size_t)t*V_ + col] = acc[m][n][i] + bv;
      }
    }
  }
}

// ---------------------------------------------------------------------------
extern "C" void kernel_launch(void* const* d_in, const int* in_sizes, int n_in,
                              void* d_out, int out_size, void* d_ws, size_t ws_size,
                              hipStream_t stream)
{
  const int*   trg    = (const int*)d_in[0];
  const float* init_h = (const float*)d_in[1];
  const float* init_c = (const float*)d_in[2];
  const float* emb    = (const float*)d_in[3];
  const float* Wh     = (const float*)d_in[4];
  const float* bh     = (const float*)d_in[5];
  const float* Wc     = (const float*)d_in[6];
  const float* bc     = (const float*)d_in[7];
  const float* Wih    = (const float*)d_in[8];
  const float* Whh    = (const float*)d_in[9];
  const float* bih    = (const float*)d_in[10];
  const float* bhh    = (const float*)d_in[11];
  const float* Wlogit = (const float*)d_in[12];
  const float* blogit = (const float*)d_in[13];
  float* out = (float*)d_out;

  // workspace layout (bytes)
  char* ws = (char*)d_ws;
  float*        xg    = (float*)(ws);               // 16,777,216
  float*        h0    = (float*)(ws + 16777216);    //     65,536
  float*        c0    = (float*)(ws + 16842752);    //     65,536
  u16*          A_buf = (u16*)  (ws + 16908288);    //  2,097,152
  u16*          h_g   = (u16*)  (ws + 19005440);    //    131,072 (2 parities)
  unsigned int* flag  = (unsigned int*)(ws + 19136512); // 2,048 (32 x 64B)
  unsigned int* gate  = (unsigned int*)(ws + 19138560); // 64 (own line)
  u16*          W16   = (u16*)  (ws + 19138624);    // 32,768,000 (optional)
  const size_t need_w16 = 19138624ull + 32768000ull;
  const bool use_w16 = (ws_size >= need_w16);

  hipLaunchKernelGGL(k_init, dim3(128), dim3(256), 0, stream,
                     init_h, init_c, Wh, bh, Wc, bc, h0, c0, flag, gate);
  if (use_w16)
    hipLaunchKernelGGL(k_cvt, dim3((V_*H_)/(256*8)), dim3(256), 0, stream,
                       Wlogit, W16);
  hipLaunchKernelGGL(k_xgates, dim3(16, 16), dim3(256), 0, stream,
                     emb, Wih, trg, bih, bhh, xg);
  if (use_w16){
    void* args[] = { (void*)&Whh, (void*)&xg, (void*)&h0, (void*)&c0,
                     (void*)&h_g, (void*)&A_buf, (void*)&flag, (void*)&gate,
                     (void*)&W16, (void*)&blogit, (void*)&out };
    hipError_t merr = hipLaunchCooperativeKernel((void*)k_mega,
                          dim3(256), dim3(512), args, 0, stream);
    if (merr != hipSuccess){
      // fallback: proven round-9 pipeline (deterministic: capacity is static)
      void* sargs[] = { (void*)&Whh, (void*)&xg, (void*)&h0, (void*)&c0,
                        (void*)&h_g, (void*)&A_buf, (void*)&flag };
      hipLaunchCooperativeKernel((void*)k_scan, dim3(NBLK_), dim3(512),
                                 sargs, 0, stream);
      hipLaunchKernelGGL(k_logits16, dim3(16, 250), dim3(256), 0, stream,
                         A_buf, W16, blogit, out);
    }
  } else {
    void* args[] = { (void*)&Whh, (void*)&xg, (void*)&h0, (void*)&c0,
                     (void*)&h_g, (void*)&A_buf, (void*)&flag };
    hipLaunchCooperativeKernel((void*)k_scan, dim3(NBLK_), dim3(512), args, 0, stream);
    hipLaunchKernelGGL(k_logits, dim3(16, 250), dim3(256), 0, stream,
                       A_buf, Wlogit, blogit, out);
  }
}

// Round 18
// 571.022 us; speedup vs baseline: 1.4983x; 1.4983x over previous
//
#include <hip/hip_runtime.h>
#include <hip/hip_cooperative_groups.h>

typedef unsigned short u16;
typedef __attribute__((ext_vector_type(8))) unsigned short us8;
typedef __attribute__((ext_vector_type(8))) __bf16 bf16x8;
typedef __attribute__((ext_vector_type(4))) float f32x4;

#define B_ 32
#define T_ 64
#define V_ 32000
#define E_ 300
#define H_ 512
#define G4_ 2048   // 4*H
#define NBLK_ 32   // scan blocks
#define NWRK_ 223  // gemm worker blocks (scan 32 + master 1 + workers 223 = 256)
#define NT_TILES 250
#define NM_TILES 16

__device__ __forceinline__ u16 f2b(float f){
  unsigned int x = __builtin_bit_cast(unsigned int, f);
  unsigned int r = (x + 0x7FFFu + ((x >> 16) & 1u)) >> 16;
  return (u16)r;
}
__device__ __forceinline__ float sigm(float x){ return 1.0f/(1.0f+expf(-x)); }

__device__ __forceinline__ void gload16(const u16* g, u16* l){
  __builtin_amdgcn_global_load_lds(
      (const __attribute__((address_space(1))) void*)g,
      (__attribute__((address_space(3))) void*)l, 16, 0, 0);
}

// ---------------------------------------------------------------------------
// Kernel 1: h0 = init_h[0] @ Wh^T + bh ; c0 = init_c[0] @ Wc^T + bc   (f32)
// Also zeroes the 32 scan flags + the aggregated gate cell every call.
// ---------------------------------------------------------------------------
__global__ __launch_bounds__(256) void k_init(
    const float* __restrict__ init_h, const float* __restrict__ init_c,
    const float* __restrict__ Wh, const float* __restrict__ bh,
    const float* __restrict__ Wc, const float* __restrict__ bc,
    float* __restrict__ h0out, float* __restrict__ c0out,
    unsigned int* __restrict__ flag, unsigned int* __restrict__ gate)
{
  if (blockIdx.x == 0){
    flag[threadIdx.x] = 0u; flag[threadIdx.x + 256] = 0u;
    if (threadIdx.x == 0) gate[0] = 0u;
  }
  int idx = blockIdx.x*blockDim.x + threadIdx.x;    // 0..32767
  int sel = idx >> 14;                              // 0: h, 1: c
  int r = idx & 16383;
  int b = r >> 9, j = r & 511;
  const float* x = (sel ? init_c : init_h) + b*H_;
  const float* w = (sel ? Wc : Wh) + (size_t)j*H_;
  const float* bias = sel ? bc : bh;
  float acc = 0.f;
  for (int k = 0; k < H_; k += 8){
    f32x4 x0 = *(const f32x4*)(x + k), x1 = *(const f32x4*)(x + k + 4);
    f32x4 w0 = *(const f32x4*)(w + k), w1 = *(const f32x4*)(w + k + 4);
    acc += x0[0]*w0[0] + x0[1]*w0[1] + x0[2]*w0[2] + x0[3]*w0[3];
    acc += x1[0]*w1[0] + x1[1]*w1[1] + x1[2]*w1[2] + x1[3]*w1[3];
  }
  acc += bias[j];
  (sel ? c0out : h0out)[b*H_ + j] = acc;
}

// ---------------------------------------------------------------------------
// Kernel 1b: W_logit f32 -> bf16 prepass (16.384M elems, 8/thread, exact grid)
// ---------------------------------------------------------------------------
__global__ __launch_bounds__(256) void k_cvt(
    const float* __restrict__ W, u16* __restrict__ W16)
{
  size_t i = ((size_t)blockIdx.x*256 + threadIdx.x)*8;
  f32x4 a = *(const f32x4*)(W + i);
  f32x4 b = *(const f32x4*)(W + i + 4);
  us8 u;
  u[0]=f2b(a[0]); u[1]=f2b(a[1]); u[2]=f2b(a[2]); u[3]=f2b(a[3]);
  u[4]=f2b(b[0]); u[5]=f2b(b[1]); u[6]=f2b(b[2]); u[7]=f2b(b[3]);
  *(us8*)(W16 + i) = u;
}

// ---------------------------------------------------------------------------
// Kernel 2: xg[t][b][g] = emb[token(b,t)] . W_ih[g] + b_ih[g] + b_hh[g]  (f32)
// MFMA GEMM, M=2048 (rows r=t*32+b gathered from embedding), N=2048, K=300.
// ---------------------------------------------------------------------------
__global__ __launch_bounds__(256) void k_xgates(
    const float* __restrict__ emb, const float* __restrict__ Wih,
    const int* __restrict__ trg, const float* __restrict__ bih,
    const float* __restrict__ bhh, float* __restrict__ xg)
{
  __shared__ u16 As[128][40];   // +8 pad: row stride 80B -> conflict-free b128
  __shared__ u16 Bs[128][40];
  const int bn0 = blockIdx.x*128, bm0 = blockIdx.y*128;
  const int tid = threadIdx.x;
  const int w = tid>>6, lane = tid&63;
  const int wr = w>>1, wc = w&1, lr = lane&15, lk = lane>>4;
  const int srow = tid>>1, half = tid&1;
  const int R = bm0 + srow;
  const int tt = R>>5, bb = R&31;
  const int token = trg[bb*T_ + tt];
  const float* arow = emb + (size_t)token*E_;
  const float* brow = Wih + (size_t)(bn0+srow)*E_;
  f32x4 acc[4][4] = {};
  for (int k0 = 0; k0 < E_; k0 += 32){
    int cbase = k0 + half*16;
    if (k0 + 32 <= E_){
      f32x4 a0=*(const f32x4*)(arow+cbase),    a1=*(const f32x4*)(arow+cbase+4);
      f32x4 a2=*(const f32x4*)(arow+cbase+8),  a3=*(const f32x4*)(arow+cbase+12);
      f32x4 b0=*(const f32x4*)(brow+cbase),    b1=*(const f32x4*)(brow+cbase+4);
      f32x4 b2=*(const f32x4*)(brow+cbase+8),  b3=*(const f32x4*)(brow+cbase+12);
      us8 ua, ub;
      ua[0]=f2b(a0[0]); ua[1]=f2b(a0[1]); ua[2]=f2b(a0[2]); ua[3]=f2b(a0[3]);
      ua[4]=f2b(a1[0]); ua[5]=f2b(a1[1]); ua[6]=f2b(a1[2]); ua[7]=f2b(a1[3]);
      ub[0]=f2b(a2[0]); ub[1]=f2b(a2[1]); ub[2]=f2b(a2[2]); ub[3]=f2b(a2[3]);
      ub[4]=f2b(a3[0]); ub[5]=f2b(a3[1]); ub[6]=f2b(a3[2]); ub[7]=f2b(a3[3]);
      *(us8*)&As[srow][half*16]   = ua;
      *(us8*)&As[srow][half*16+8] = ub;
      us8 va, vb;
      va[0]=f2b(b0[0]); va[1]=f2b(b0[1]); va[2]=f2b(b0[2]); va[3]=f2b(b0[3]);
      va[4]=f2b(b1[0]); va[5]=f2b(b1[1]); va[6]=f2b(b1[2]); va[7]=f2b(b1[3]);
      vb[0]=f2b(b2[0]); vb[1]=f2b(b2[1]); vb[2]=f2b(b2[2]); vb[3]=f2b(b2[3]);
      vb[4]=f2b(b3[0]); vb[5]=f2b(b3[1]); vb[6]=f2b(b3[2]); vb[7]=f2b(b3[3]);
      *(us8*)&Bs[srow][half*16]   = va;
      *(us8*)&Bs[srow][half*16+8] = vb;
    } else {
      for (int i = 0; i < 16; i++){
        int c = cbase + i;
        As[srow][half*16+i] = (c < E_) ? f2b(arow[c]) : (u16)0;
        Bs[srow][half*16+i] = (c < E_) ? f2b(brow[c]) : (u16)0;
      }
    }
    __syncthreads();
    bf16x8 af[4], bfr[4];
    #pragma unroll
    for (int m = 0; m < 4; m++) af[m] = *(const bf16x8*)&As[wr*64 + m*16 + lr][lk*8];
    #pragma unroll
    for (int n = 0; n < 4; n++) bfr[n] = *(const bf16x8*)&Bs[wc*64 + n*16 + lr][lk*8];
    #pragma unroll
    for (int m = 0; m < 4; m++)
      #pragma unroll
      for (int n = 0; n < 4; n++)
        acc[m][n] = __builtin_amdgcn_mfma_f32_16x16x32_bf16(af[m], bfr[n], acc[m][n], 0, 0, 0);
    __syncthreads();
  }
  #pragma unroll
  for (int n = 0; n < 4; n++){
    int col = bn0 + wc*64 + n*16 + lr;
    float bv = bih[col] + bhh[col];
    #pragma unroll
    for (int m = 0; m < 4; m++){
      #pragma unroll
      for (int i = 0; i < 4; i++){
        int row = bm0 + wr*64 + m*16 + lk*4 + i;
        xg[(size_t)row*G4_ + col] = acc[m][n][i] + bv;
      }
    }
  }
}

// ---------------------------------------------------------------------------
// Mega kernel (cooperative, 256 blocks x 512 thr).
// __launch_bounds__(512) with NO min-waves arg: rounds 11-17 used (512,4),
// which made the allocator pick 64 VGPR and SPILL the scan's bw[16]
// (64 VGPR) -> +~2us/step. Capacity is fine at 1 block/CU regardless.
//   block  [0,32):  LSTM scan (round-9 structure) + final release flag=65.
//   block  32:      GATE MASTER: polls 32 scan flags (ACQUIRE, 1 wave),
//                   publishes group level 1..4 to ONE gate line (RELEASE).
//   blocks [33,256): 223 GEMM workers, 4 gate groups (q: mt in [4q,4q+4),
//                   flags >= 16q+17 certify A rows; final 65). Workers poll
//                   the single gate line RELAXED (1 lane) -- R17's ACQUIRE
//                   spin invalidated every XCD L2 continuously (794us).
//                   One all-thread acquire fence per gate-change.
//                   Within a group: nt-outer, mt-inner (W panel reused 4x
//                   from L2 before the 262MB output stream evicts it).
// LDS: manual union, 41472 B (scan: 33280+8192; gemm: 2x8192).
// ---------------------------------------------------------------------------
__global__ __launch_bounds__(512) void k_mega(
    const float* __restrict__ Whh, const float* __restrict__ xg,
    const float* __restrict__ h0, const float* __restrict__ c0,
    u16* __restrict__ h_g, u16* __restrict__ A_buf,
    unsigned int* __restrict__ flag, unsigned int* __restrict__ gate,
    const u16* __restrict__ W16, const float* __restrict__ bias,
    float* __restrict__ out)
{
  __shared__ __align__(16) char smem[41472];
  const int tid = threadIdx.x;

  if (blockIdx.x < NBLK_){
    // ======================= SCAN PATH (round-9 verbatim) ==================
    u16 (*hl)[520] = (u16(*)[520])smem;
    float (*gb)[32][16] = (float(*)[32][16])(smem + 33280);
    const int bj = blockIdx.x;
    const int wv = tid >> 6, lane = tid & 63;
    const int g = wv >> 1, m = wv & 1;
    const int lr = lane & 15, lk = lane >> 4;

    bf16x8 bw[16];
    {
      const float* wsrc = Whh + (size_t)(g*H_ + bj*16 + lr)*H_;
      #pragma unroll
      for (int ks = 0; ks < 16; ks++){
        f32x4 w0 = *(const f32x4*)(wsrc + ks*32 + lk*8);
        f32x4 w1 = *(const f32x4*)(wsrc + ks*32 + lk*8 + 4);
        us8 u;
        u[0]=f2b(w0[0]); u[1]=f2b(w0[1]); u[2]=f2b(w0[2]); u[3]=f2b(w0[3]);
        u[4]=f2b(w1[0]); u[5]=f2b(w1[1]); u[6]=f2b(w1[2]); u[7]=f2b(w1[3]);
        bw[ks] = __builtin_bit_cast(bf16x8, u);
      }
    }
    const int ub = tid >> 4, uj = tid & 15;
    float c_reg = c0[ub*H_ + bj*16 + uj];

    {
      int r = tid >> 4, seg = tid & 15;
      const float* src = h0 + r*H_ + seg*32;
      #pragma unroll
      for (int q = 0; q < 4; q++){
        f32x4 v0 = *(const f32x4*)(src + q*8);
        f32x4 v1 = *(const f32x4*)(src + q*8 + 4);
        us8 u;
        u[0]=f2b(v0[0]); u[1]=f2b(v0[1]); u[2]=f2b(v0[2]); u[3]=f2b(v0[3]);
        u[4]=f2b(v1[0]); u[5]=f2b(v1[1]); u[6]=f2b(v1[2]); u[7]=f2b(v1[3]);
        *(us8*)&hl[r][seg*32 + q*8] = u;
      }
    }
    __syncthreads();

    for (int t = 0; t < T_; t++){
      const float* xr = xg + (size_t)t*(B_*G4_) + ub*G4_ + bj*16 + uj;
      float x0 = xr[0*H_], x1 = xr[1*H_], x2 = xr[2*H_], x3 = xr[3*H_];

      f32x4 acc = {0.f, 0.f, 0.f, 0.f};
      #pragma unroll
      for (int ks = 0; ks < 16; ks++){
        bf16x8 a = *(const bf16x8*)&hl[m*16 + lr][ks*32 + lk*8];
        acc = __builtin_amdgcn_mfma_f32_16x16x32_bf16(a, bw[ks], acc, 0, 0, 0);
      }
      #pragma unroll
      for (int i = 0; i < 4; i++)
        gb[g][m*16 + lk*4 + i][lr] = acc[i];
      __syncthreads();

      float gi = sigm(gb[0][ub][uj] + x0);
      float gf = sigm(gb[1][ub][uj] + x1);
      float gg = tanhf(gb[2][ub][uj] + x2);
      float go = sigm(gb[3][ub][uj] + x3);
      c_reg = gf*c_reg + gi*gg;
      float h = go * tanhf(c_reg);
      int p = (t+1) & 1;
      h_g[p*(B_*H_) + bj*(B_*16) + tid] = f2b(h);

      __syncthreads();   // drains h_g stores (vmcnt0) before release
      if (t < T_-1 && tid == 0)
        __hip_atomic_store(&flag[bj*16], (unsigned)(t+1),
                           __ATOMIC_RELEASE, __HIP_MEMORY_SCOPE_AGENT);

      A_buf[(size_t)t*(B_*H_) + ub*H_ + bj*16 + uj] = f2b(tanhf(h));
      if (t == T_-1) break;

      if (tid < 64){
        unsigned want = (unsigned)(t+1), guard = 0;
        while (__hip_atomic_load(&flag[(tid&31)*16], __ATOMIC_ACQUIRE,
                                 __HIP_MEMORY_SCOPE_AGENT) < want
               && guard < (1u<<18)) { __builtin_amdgcn_s_sleep(1); ++guard; }
      }
      __syncthreads();

      {
        int r = tid >> 4, seg = tid & 15;
        const u16* hb = h_g + p*(B_*H_);
        const u16* p0 = hb + (seg*2)  *(B_*16) + r*16;
        const u16* p1 = hb + (seg*2+1)*(B_*16) + r*16;
        us8 v0 = *(const us8*)(p0);
        us8 v1 = *(const us8*)(p0 + 8);
        us8 v2 = *(const us8*)(p1);
        us8 v3 = *(const us8*)(p1 + 8);
        *(us8*)&hl[r][seg*32]      = v0;
        *(us8*)&hl[r][seg*32 + 8]  = v1;
        *(us8*)&hl[r][seg*32 + 16] = v2;
        *(us8*)&hl[r][seg*32 + 24] = v3;
      }
      __syncthreads();
    }
    // final publish: A of t=63 (and all prior) flushed by this release
    __syncthreads();   // drain last A_buf stores
    if (tid == 0)
      __hip_atomic_store(&flag[bj*16], 65u,
                         __ATOMIC_RELEASE, __HIP_MEMORY_SCOPE_AGENT);
  } else if (blockIdx.x == NBLK_){
    // ======================= GATE MASTER ==================================
    if (tid < 64){
      for (int q = 0; q < 4; q++){
        unsigned want = (q < 3) ? (unsigned)(16*q + 17) : 65u;
        unsigned guard = 0;
        for (;;){
          unsigned v = __hip_atomic_load(&flag[(tid&31)*16], __ATOMIC_ACQUIRE,
                                         __HIP_MEMORY_SCOPE_AGENT);
          if (__all(v >= want) || guard > (1u<<21)) break;
          __builtin_amdgcn_s_sleep(2); ++guard;
        }
        if (tid == 0)
          __hip_atomic_store(gate, (unsigned)(q+1),
                             __ATOMIC_RELEASE, __HIP_MEMORY_SCOPE_AGENT);
      }
    }
  } else {
    // =============== GEMM WORKERS (nt-outer within 4 gate groups) =========
    u16* As = (u16*)smem;
    u16* Bs = (u16*)(smem + 8192);
    const int w = tid>>6, lane = tid&63;
    const int wr = w & 1, wc = w >> 1;               // 2 x 4 wave grid
    const int lr = lane&15, lk = lane>>4;
    const int srow = w*16 + (lane>>2);               // 0..127
    const int cb   = ((lane&3)*16) ^ (((srow>>1)&3)<<4);
    u16* adst = &As[(w*16)*32];                      // wave rows [w*16,w*16+16)
    u16* bdst = &Bs[(w*16)*32];
    const int wid = (int)blockIdx.x - (NBLK_ + 1);   // 0..222

    for (int q = 0; q < 4; q++){
      if (tid == 0){
        unsigned guard = 0;
        while (__hip_atomic_load(gate, __ATOMIC_RELAXED,
                                 __HIP_MEMORY_SCOPE_AGENT) < (unsigned)(q+1)
               && guard < (1u<<19)) { __builtin_amdgcn_s_sleep(16); ++guard; }
      }
      __syncthreads();                                  // observation shared
      __builtin_amdgcn_fence(__ATOMIC_ACQUIRE, "agent"); // one inv per gate

      for (int nt = wid; nt < NT_TILES; nt += NWRK_){
        const int bn0 = nt*128;
        const u16* bpt = W16 + (size_t)(bn0+srow)*H_ + (cb>>1);
        for (int mtl = 0; mtl < 4; mtl++){          // W panel reused 4x (L2)
          const int bm0 = (q*4 + mtl)*128;
          const u16* apt = A_buf + (size_t)(bm0+srow)*H_ + (cb>>1);
          f32x4 acc[4][2] = {};
          for (int k0 = 0; k0 < H_; k0 += 32){
            gload16(apt + k0, adst);
            gload16(bpt + k0, bdst);
            __syncthreads();
            bf16x8 af[4], bfr[2];
            #pragma unroll
            for (int m = 0; m < 4; m++){
              int row = wr*64 + m*16 + lr;
              af[m] = *(const bf16x8*)((const char*)As + row*64 + ((lk*16) ^ (((row>>1)&3)<<4)));
            }
            #pragma unroll
            for (int n = 0; n < 2; n++){
              int row = wc*32 + n*16 + lr;
              bfr[n] = *(const bf16x8*)((const char*)Bs + row*64 + ((lk*16) ^ (((row>>1)&3)<<4)));
            }
            #pragma unroll
            for (int m = 0; m < 4; m++)
              #pragma unroll
              for (int n = 0; n < 2; n++)
                acc[m][n] = __builtin_amdgcn_mfma_f32_16x16x32_bf16(af[m], bfr[n], acc[m][n], 0, 0, 0);
            __syncthreads();
          }
          #pragma unroll
          for (int n = 0; n < 2; n++){
            int col = bn0 + wc*32 + n*16 + lr;
            float bv = bias[col];
            #pragma unroll
            for (int m = 0; m < 4; m++){
              #pragma unroll
              for (int i = 0; i < 4; i++){
                int row = bm0 + wr*64 + m*16 + lk*4 + i;
                int t = row>>5, b = row&31;
                __builtin_nontemporal_store(acc[m][n][i] + bv,
                    &out[(size_t)b*((size_t)T_*V_) + (size_t)t*V_ + col]);
              }
            }
          }
        }
      }
    }
  }
}

// ---------------------------------------------------------------------------
// Standalone fallback kernels (round-9 proven, 499us total path).
// ---------------------------------------------------------------------------
__global__ __launch_bounds__(512) void k_scan(
    const float* __restrict__ Whh, const float* __restrict__ xg,
    const float* __restrict__ h0, const float* __restrict__ c0,
    u16* __restrict__ h_g, u16* __restrict__ A_buf,
    unsigned int* __restrict__ flag)
{
  __shared__ u16 hl[32][520];
  __shared__ float gb[4][32][16];
  const int bj = blockIdx.x;
  const int tid = threadIdx.x;
  const int wv = tid >> 6, lane = tid & 63;
  const int g = wv >> 1, m = wv & 1;
  const int lr = lane & 15, lk = lane >> 4;
  bf16x8 bw[16];
  {
    const float* wsrc = Whh + (size_t)(g*H_ + bj*16 + lr)*H_;
    #pragma unroll
    for (int ks = 0; ks < 16; ks++){
      f32x4 w0 = *(const f32x4*)(wsrc + ks*32 + lk*8);
      f32x4 w1 = *(const f32x4*)(wsrc + ks*32 + lk*8 + 4);
      us8 u;
      u[0]=f2b(w0[0]); u[1]=f2b(w0[1]); u[2]=f2b(w0[2]); u[3]=f2b(w0[3]);
      u[4]=f2b(w1[0]); u[5]=f2b(w1[1]); u[6]=f2b(w1[2]); u[7]=f2b(w1[3]);
      bw[ks] = __builtin_bit_cast(bf16x8, u);
    }
  }
  const int ub = tid >> 4, uj = tid & 15;
  float c_reg = c0[ub*H_ + bj*16 + uj];
  {
    int r = tid >> 4, seg = tid & 15;
    const float* src = h0 + r*H_ + seg*32;
    #pragma unroll
    for (int q = 0; q < 4; q++){
      f32x4 v0 = *(const f32x4*)(src + q*8);
      f32x4 v1 = *(const f32x4*)(src + q*8 + 4);
      us8 u;
      u[0]=f2b(v0[0]); u[1]=f2b(v0[1]); u[2]=f2b(v0[2]); u[3]=f2b(v0[3]);
      u[4]=f2b(v1[0]); u[5]=f2b(v1[1]); u[6]=f2b(v1[2]); u[7]=f2b(v1[3]);
      *(us8*)&hl[r][seg*32 + q*8] = u;
    }
  }
  __syncthreads();
  for (int t = 0; t < T_; t++){
    const float* xr = xg + (size_t)t*(B_*G4_) + ub*G4_ + bj*16 + uj;
    float x0 = xr[0*H_], x1 = xr[1*H_], x2 = xr[2*H_], x3 = xr[3*H_];
    f32x4 acc = {0.f, 0.f, 0.f, 0.f};
    #pragma unroll
    for (int ks = 0; ks < 16; ks++){
      bf16x8 a = *(const bf16x8*)&hl[m*16 + lr][ks*32 + lk*8];
      acc = __builtin_amdgcn_mfma_f32_16x16x32_bf16(a, bw[ks], acc, 0, 0, 0);
    }
    #pragma unroll
    for (int i = 0; i < 4; i++)
      gb[g][m*16 + lk*4 + i][lr] = acc[i];
    __syncthreads();
    float gi = sigm(gb[0][ub][uj] + x0);
    float gf = sigm(gb[1][ub][uj] + x1);
    float gg = tanhf(gb[2][ub][uj] + x2);
    float go = sigm(gb[3][ub][uj] + x3);
    c_reg = gf*c_reg + gi*gg;
    float h = go * tanhf(c_reg);
    int p = (t+1) & 1;
    h_g[p*(B_*H_) + bj*(B_*16) + tid] = f2b(h);
    __syncthreads();
    if (t < T_-1 && tid == 0)
      __hip_atomic_store(&flag[bj*16], (unsigned)(t+1),
                         __ATOMIC_RELEASE, __HIP_MEMORY_SCOPE_AGENT);
    A_buf[(size_t)t*(B_*H_) + ub*H_ + bj*16 + uj] = f2b(tanhf(h));
    if (t == T_-1) break;
    if (tid < 64){
      unsigned want = (unsigned)(t+1), guard = 0;
      while (__hip_atomic_load(&flag[(tid&31)*16], __ATOMIC_ACQUIRE,
                               __HIP_MEMORY_SCOPE_AGENT) < want
             && guard < (1u<<18)) { __builtin_amdgcn_s_sleep(1); ++guard; }
    }
    __syncthreads();
    {
      int r = tid >> 4, seg = tid & 15;
      const u16* hb = h_g + p*(B_*H_);
      const u16* p0 = hb + (seg*2)  *(B_*16) + r*16;
      const u16* p1 = hb + (seg*2+1)*(B_*16) + r*16;
      us8 v0 = *(const us8*)(p0);
      us8 v1 = *(const us8*)(p0 + 8);
      us8 v2 = *(const us8*)(p1);
      us8 v3 = *(const us8*)(p1 + 8);
      *(us8*)&hl[r][seg*32]      = v0;
      *(us8*)&hl[r][seg*32 + 8]  = v1;
      *(us8*)&hl[r][seg*32 + 16] = v2;
      *(us8*)&hl[r][seg*32 + 24] = v3;
    }
    __syncthreads();
  }
}

__global__ __launch_bounds__(256) void k_logits16(
    const u16* __restrict__ A, const u16* __restrict__ W16,
    const float* __restrict__ bias, float* __restrict__ out)
{
  __shared__ u16 As[128*32];
  __shared__ u16 Bs[128*32];
  int bid = blockIdx.y*16 + blockIdx.x;      // 0..3999
  int nbid = (bid & 7)*500 + (bid >> 3);     // bijective (4000 = 8*500)
  const int bm0 = (nbid & 15)*128;
  const int bn0 = (nbid >> 4)*128;
  const int tid = threadIdx.x;
  const int w = tid>>6, lane = tid&63;
  const int wr = w>>1, wc = w&1, lr = lane&15, lk = lane>>4;
  const int srow = w*32 + (lane>>2);
  const int cb   = ((lane&3)*16) ^ (((srow>>1)&3)<<4);
  const u16* aptr = A   + (size_t)(bm0+srow)*H_ + (cb>>1);
  const u16* bptr = W16 + (size_t)(bn0+srow)*H_ + (cb>>1);
  u16* adst0 = &As[(w*32)*32];
  u16* adst1 = &As[(w*32+16)*32];
  u16* bdst0 = &Bs[(w*32)*32];
  u16* bdst1 = &Bs[(w*32+16)*32];
  f32x4 acc[4][4] = {};
  for (int k0 = 0; k0 < H_; k0 += 32){
    gload16(aptr + k0,          adst0);
    gload16(aptr + k0 + 16*H_,  adst1);
    gload16(bptr + k0,          bdst0);
    gload16(bptr + k0 + 16*H_,  bdst1);
    __syncthreads();
    bf16x8 af[4], bfr[4];
    #pragma unroll
    for (int m = 0; m < 4; m++){
      int row = wr*64 + m*16 + lr;
      af[m] = *(const bf16x8*)((const char*)As + row*64 + ((lk*16) ^ (((row>>1)&3)<<4)));
    }
    #pragma unroll
    for (int n = 0; n < 4; n++){
      int row = wc*64 + n*16 + lr;
      bfr[n] = *(const bf16x8*)((const char*)Bs + row*64 + ((lk*16) ^ (((row>>1)&3)<<4)));
    }
    #pragma unroll
    for (int m = 0; m < 4; m++)
      #pragma unroll
      for (int n = 0; n < 4; n++)
        acc[m][n] = __builtin_amdgcn_mfma_f32_16x16x32_bf16(af[m], bfr[n], acc[m][n], 0, 0, 0);
    __syncthreads();
  }
  #pragma unroll
  for (int n = 0; n < 4; n++){
    int col = bn0 + wc*64 + n*16 + lr;
    float bv = bias[col];
    #pragma unroll
    for (int m = 0; m < 4; m++){
      #pragma unroll
      for (int i = 0; i < 4; i++){
        int row = bm0 + wr*64 + m*16 + lk*4 + i;
        int t = row>>5, b = row&31;
        __builtin_nontemporal_store(acc[m][n][i] + bv,
            &out[(size_t)b*((size_t)T_*V_) + (size_t)t*V_ + col]);
      }
    }
  }
}

__global__ __launch_bounds__(256) void k_logits(
    const u16* __restrict__ A, const float* __restrict__ W,
    const float* __restrict__ bias, float* __restrict__ out)
{
  __shared__ u16 As[128][40];
  __shared__ u16 Bs[128][40];
  const int bm0 = blockIdx.x*128, bn0 = blockIdx.y*128;
  const int tid = threadIdx.x;
  const int w = tid>>6, lane = tid&63;
  const int wr = w>>1, wc = w&1, lr = lane&15, lk = lane>>4;
  const int srow = tid>>1, half = tid&1;
  const u16*   arow = A + (size_t)(bm0+srow)*H_;
  const float* brow = W + (size_t)(bn0+srow)*H_;
  f32x4 acc[4][4] = {};
  for (int k0 = 0; k0 < H_; k0 += 32){
    us8 a0 = *(const us8*)(arow + k0 + half*16);
    us8 a1 = *(const us8*)(arow + k0 + half*16 + 8);
    f32x4 b0 = *(const f32x4*)(brow + k0 + half*16);
    f32x4 b1 = *(const f32x4*)(brow + k0 + half*16 + 4);
    f32x4 b2 = *(const f32x4*)(brow + k0 + half*16 + 8);
    f32x4 b3 = *(const f32x4*)(brow + k0 + half*16 + 12);
    *(us8*)&As[srow][half*16]   = a0;
    *(us8*)&As[srow][half*16+8] = a1;
    us8 vb0, vb1;
    vb0[0]=f2b(b0[0]); vb0[1]=f2b(b0[1]); vb0[2]=f2b(b0[2]); vb0[3]=f2b(b0[3]);
    vb0[4]=f2b(b1[0]); vb0[5]=f2b(b1[1]); vb0[6]=f2b(b1[2]); vb0[7]=f2b(b1[3]);
    vb1[0]=f2b(b2[0]); vb1[1]=f2b(b2[1]); vb1[2]=f2b(b2[2]); vb1[3]=f2b(b2[3]);
    vb1[4]=f2b(b3[0]); vb1[5]=f2b(b3[1]); vb1[6]=f2b(b3[2]); vb1[7]=f2b(b3[3]);
    *(us8*)&Bs[srow][half*16]   = vb0;
    *(us8*)&Bs[srow][half*16+8] = vb1;
    __syncthreads();
    bf16x8 af[4], bfr[4];
    #pragma unroll
    for (int m = 0; m < 4; m++) af[m] = *(const bf16x8*)&As[wr*64 + m*16 + lr][lk*8];
    #pragma unroll
    for (int n = 0; n < 4; n++) bfr[n] = *(const bf16x8*)&Bs[wc*64 + n*16 + lr][lk*8];
    #pragma unroll
    for (int m = 0; m < 4; m++)
      #pragma unroll
      for (int n = 0; n < 4; n++)
        acc[m][n] = __builtin_amdgcn_mfma_f32_16x16x32_bf16(af[m], bfr[n], acc[m][n], 0, 0, 0);
    __syncthreads();
  }
  #pragma unroll
  for (int n = 0; n < 4; n++){
    int col = bn0 + wc*64 + n*16 + lr;
    float bv = bias[col];
    #pragma unroll
    for (int m = 0; m < 4; m++){
      #pragma unroll
      for (int i = 0; i < 4; i++){
        int row = bm0 + wr*64 + m*16 + lk*4 + i;
        int t = row>>5, b = row&31;
        out[(size_t)b*((size_t)T_*V_) + (size_t)t*V_ + col] = acc[m][n][i] + bv;
      }
    }
  }
}

// ---------------------------------------------------------------------------
extern "C" void kernel_launch(void* const* d_in, const int* in_sizes, int n_in,
                              void* d_out, int out_size, void* d_ws, size_t ws_size,
                              hipStream_t stream)
{
  const int*   trg    = (const int*)d_in[0];
  const float* init_h = (const float*)d_in[1];
  const float* init_c = (const float*)d_in[2];
  const float* emb    = (const float*)d_in[3];
  const float* Wh     = (const float*)d_in[4];
  const float* bh     = (const float*)d_in[5];
  const float* Wc     = (const float*)d_in[6];
  const float* bc     = (const float*)d_in[7];
  const float* Wih    = (const float*)d_in[8];
  const float* Whh    = (const float*)d_in[9];
  const float* bih    = (const float*)d_in[10];
  const float* bhh    = (const float*)d_in[11];
  const float* Wlogit = (const float*)d_in[12];
  const float* blogit = (const float*)d_in[13];
  float* out = (float*)d_out;

  // workspace layout (bytes)
  char* ws = (char*)d_ws;
  float*        xg    = (float*)(ws);               // 16,777,216
  float*        h0    = (float*)(ws + 16777216);    //     65,536
  float*        c0    = (float*)(ws + 16842752);    //     65,536
  u16*          A_buf = (u16*)  (ws + 16908288);    //  2,097,152
  u16*          h_g   = (u16*)  (ws + 19005440);    //    131,072 (2 parities)
  unsigned int* flag  = (unsigned int*)(ws + 19136512); // 2,048 (32 x 64B)
  unsigned int* gate  = (unsigned int*)(ws + 19138560); // 64 (own line)
  u16*          W16   = (u16*)  (ws + 19138624);    // 32,768,000 (optional)
  const size_t need_w16 = 19138624ull + 32768000ull;
  const bool use_w16 = (ws_size >= need_w16);

  hipLaunchKernelGGL(k_init, dim3(128), dim3(256), 0, stream,
                     init_h, init_c, Wh, bh, Wc, bc, h0, c0, flag, gate);
  if (use_w16)
    hipLaunchKernelGGL(k_cvt, dim3((V_*H_)/(256*8)), dim3(256), 0, stream,
                       Wlogit, W16);
  hipLaunchKernelGGL(k_xgates, dim3(16, 16), dim3(256), 0, stream,
                     emb, Wih, trg, bih, bhh, xg);
  if (use_w16){
    void* args[] = { (void*)&Whh, (void*)&xg, (void*)&h0, (void*)&c0,
                     (void*)&h_g, (void*)&A_buf, (void*)&flag, (void*)&gate,
                     (void*)&W16, (void*)&blogit, (void*)&out };
    hipError_t merr = hipLaunchCooperativeKernel((void*)k_mega,
                          dim3(256), dim3(512), args, 0, stream);
    if (merr != hipSuccess){
      // fallback: proven round-9 pipeline (deterministic: capacity is static)
      void* sargs[] = { (void*)&Whh, (void*)&xg, (void*)&h0, (void*)&c0,
                        (void*)&h_g, (void*)&A_buf, (void*)&flag };
      hipLaunchCooperativeKernel((void*)k_scan, dim3(NBLK_), dim3(512),
                                 sargs, 0, stream);
      hipLaunchKernelGGL(k_logits16, dim3(16, 250), dim3(256), 0, stream,
                         A_buf, W16, blogit, out);
    }
  } else {
    void* args[] = { (void*)&Whh, (void*)&xg, (void*)&h0, (void*)&c0,
                     (void*)&h_g, (void*)&A_buf, (void*)&flag };
    hipLaunchCooperativeKernel((void*)k_scan, dim3(NBLK_), dim3(512), args, 0, stream);
    hipLaunchKernelGGL(k_logits, dim3(16, 250), dim3(256), 0, stream,
                       A_buf, Wlogit, blogit, out);
  }
}

// Round 19
// 453.533 us; speedup vs baseline: 1.8864x; 1.2591x over previous
//
#include <hip/hip_runtime.h>
#include <hip/hip_cooperative_groups.h>

typedef unsigned short u16;
typedef __attribute__((ext_vector_type(8))) unsigned short us8;
typedef __attribute__((ext_vector_type(8))) __bf16 bf16x8;
typedef __attribute__((ext_vector_type(4))) float f32x4;

#define B_ 32
#define T_ 64
#define V_ 32000
#define E_ 300
#define H_ 512
#define G4_ 2048   // 4*H
#define NBLK_ 32   // scan blocks
#define NG_   224  // gemm blocks in mega kernel (total 256 = guaranteed capacity)
#define NT_TILES 250
#define NM_TILES 16

__device__ __forceinline__ u16 f2b(float f){
  unsigned int x = __builtin_bit_cast(unsigned int, f);
  unsigned int r = (x + 0x7FFFu + ((x >> 16) & 1u)) >> 16;
  return (u16)r;
}
__device__ __forceinline__ float sigm(float x){ return 1.0f/(1.0f+expf(-x)); }

__device__ __forceinline__ void gload16(const u16* g, u16* l){
  __builtin_amdgcn_global_load_lds(
      (const __attribute__((address_space(1))) void*)g,
      (__attribute__((address_space(3))) void*)l, 16, 0, 0);
}

// ---------------------------------------------------------------------------
// Kernel 1: h0 = init_h[0] @ Wh^T + bh ; c0 = init_c[0] @ Wc^T + bc   (f32)
// Also zeroes the 32 scan barrier flags (padded 64B apart) every call.
// ---------------------------------------------------------------------------
__global__ __launch_bounds__(256) void k_init(
    const float* __restrict__ init_h, const float* __restrict__ init_c,
    const float* __restrict__ Wh, const float* __restrict__ bh,
    const float* __restrict__ Wc, const float* __restrict__ bc,
    float* __restrict__ h0out, float* __restrict__ c0out,
    unsigned int* __restrict__ flag)
{
  if (blockIdx.x == 0){ flag[threadIdx.x] = 0u; flag[threadIdx.x + 256] = 0u; }
  int idx = blockIdx.x*blockDim.x + threadIdx.x;    // 0..32767
  int sel = idx >> 14;                              // 0: h, 1: c
  int r = idx & 16383;
  int b = r >> 9, j = r & 511;
  const float* x = (sel ? init_c : init_h) + b*H_;
  const float* w = (sel ? Wc : Wh) + (size_t)j*H_;
  const float* bias = sel ? bc : bh;
  float acc = 0.f;
  for (int k = 0; k < H_; k += 8){
    f32x4 x0 = *(const f32x4*)(x + k), x1 = *(const f32x4*)(x + k + 4);
    f32x4 w0 = *(const f32x4*)(w + k), w1 = *(const f32x4*)(w + k + 4);
    acc += x0[0]*w0[0] + x0[1]*w0[1] + x0[2]*w0[2] + x0[3]*w0[3];
    acc += x1[0]*w1[0] + x1[1]*w1[1] + x1[2]*w1[2] + x1[3]*w1[3];
  }
  acc += bias[j];
  (sel ? c0out : h0out)[b*H_ + j] = acc;
}

// ---------------------------------------------------------------------------
// Kernel 1b: W_logit f32 -> bf16 prepass (16.384M elems, 8/thread, exact grid)
// ---------------------------------------------------------------------------
__global__ __launch_bounds__(256) void k_cvt(
    const float* __restrict__ W, u16* __restrict__ W16)
{
  size_t i = ((size_t)blockIdx.x*256 + threadIdx.x)*8;
  f32x4 a = *(const f32x4*)(W + i);
  f32x4 b = *(const f32x4*)(W + i + 4);
  us8 u;
  u[0]=f2b(a[0]); u[1]=f2b(a[1]); u[2]=f2b(a[2]); u[3]=f2b(a[3]);
  u[4]=f2b(b[0]); u[5]=f2b(b[1]); u[6]=f2b(b[2]); u[7]=f2b(b[3]);
  *(us8*)(W16 + i) = u;
}

// ---------------------------------------------------------------------------
// Kernel 2: xg[t][b][g] = emb[token(b,t)] . W_ih[g] + b_ih[g] + b_hh[g]  (f32)
// MFMA GEMM, M=2048 (rows r=t*32+b gathered from embedding), N=2048, K=300.
// ---------------------------------------------------------------------------
__global__ __launch_bounds__(256) void k_xgates(
    const float* __restrict__ emb, const float* __restrict__ Wih,
    const int* __restrict__ trg, const float* __restrict__ bih,
    const float* __restrict__ bhh, float* __restrict__ xg)
{
  __shared__ u16 As[128][40];   // +8 pad: row stride 80B -> conflict-free b128
  __shared__ u16 Bs[128][40];
  const int bn0 = blockIdx.x*128, bm0 = blockIdx.y*128;
  const int tid = threadIdx.x;
  const int w = tid>>6, lane = tid&63;
  const int wr = w>>1, wc = w&1, lr = lane&15, lk = lane>>4;
  const int srow = tid>>1, half = tid&1;
  const int R = bm0 + srow;
  const int tt = R>>5, bb = R&31;
  const int token = trg[bb*T_ + tt];
  const float* arow = emb + (size_t)token*E_;
  const float* brow = Wih + (size_t)(bn0+srow)*E_;
  f32x4 acc[4][4] = {};
  for (int k0 = 0; k0 < E_; k0 += 32){
    int cbase = k0 + half*16;
    if (k0 + 32 <= E_){
      f32x4 a0=*(const f32x4*)(arow+cbase),    a1=*(const f32x4*)(arow+cbase+4);
      f32x4 a2=*(const f32x4*)(arow+cbase+8),  a3=*(const f32x4*)(arow+cbase+12);
      f32x4 b0=*(const f32x4*)(brow+cbase),    b1=*(const f32x4*)(brow+cbase+4);
      f32x4 b2=*(const f32x4*)(brow+cbase+8),  b3=*(const f32x4*)(brow+cbase+12);
      us8 ua, ub;
      ua[0]=f2b(a0[0]); ua[1]=f2b(a0[1]); ua[2]=f2b(a0[2]); ua[3]=f2b(a0[3]);
      ua[4]=f2b(a1[0]); ua[5]=f2b(a1[1]); ua[6]=f2b(a1[2]); ua[7]=f2b(a1[3]);
      ub[0]=f2b(a2[0]); ub[1]=f2b(a2[1]); ub[2]=f2b(a2[2]); ub[3]=f2b(a2[3]);
      ub[4]=f2b(a3[0]); ub[5]=f2b(a3[1]); ub[6]=f2b(a3[2]); ub[7]=f2b(a3[3]);
      *(us8*)&As[srow][half*16]   = ua;
      *(us8*)&As[srow][half*16+8] = ub;
      us8 va, vb;
      va[0]=f2b(b0[0]); va[1]=f2b(b0[1]); va[2]=f2b(b0[2]); va[3]=f2b(b0[3]);
      va[4]=f2b(b1[0]); va[5]=f2b(b1[1]); va[6]=f2b(b1[2]); va[7]=f2b(b1[3]);
      vb[0]=f2b(b2[0]); vb[1]=f2b(b2[1]); vb[2]=f2b(b2[2]); vb[3]=f2b(b2[3]);
      vb[4]=f2b(b3[0]); vb[5]=f2b(b3[1]); vb[6]=f2b(b3[2]); vb[7]=f2b(b3[3]);
      *(us8*)&Bs[srow][half*16]   = va;
      *(us8*)&Bs[srow][half*16+8] = vb;
    } else {
      for (int i = 0; i < 16; i++){
        int c = cbase + i;
        As[srow][half*16+i] = (c < E_) ? f2b(arow[c]) : (u16)0;
        Bs[srow][half*16+i] = (c < E_) ? f2b(brow[c]) : (u16)0;
      }
    }
    __syncthreads();
    bf16x8 af[4], bfr[4];
    #pragma unroll
    for (int m = 0; m < 4; m++) af[m] = *(const bf16x8*)&As[wr*64 + m*16 + lr][lk*8];
    #pragma unroll
    for (int n = 0; n < 4; n++) bfr[n] = *(const bf16x8*)&Bs[wc*64 + n*16 + lr][lk*8];
    #pragma unroll
    for (int m = 0; m < 4; m++)
      #pragma unroll
      for (int n = 0; n < 4; n++)
        acc[m][n] = __builtin_amdgcn_mfma_f32_16x16x32_bf16(af[m], bfr[n], acc[m][n], 0, 0, 0);
    __syncthreads();
  }
  #pragma unroll
  for (int n = 0; n < 4; n++){
    int col = bn0 + wc*64 + n*16 + lr;
    float bv = bih[col] + bhh[col];
    #pragma unroll
    for (int m = 0; m < 4; m++){
      #pragma unroll
      for (int i = 0; i < 4; i++){
        int row = bm0 + wr*64 + m*16 + lk*4 + i;
        xg[(size_t)row*G4_ + col] = acc[m][n][i] + bv;
      }
    }
  }
}

// ---------------------------------------------------------------------------
// Mega kernel (cooperative, 256 blocks x 512 thr) -- EXACT round-15-measured
// structure (399us with bw spilled), with the ONE fix: __launch_bounds__(512)
// without the min-waves arg. (512,4) forced a 64-VGPR allocation that
// spilled the scan's bw[16] (64 VGPR) to scratch, ~+2us/step (R6 mechanism;
// confirmed R18: removing it gives VGPR_Count=128). Capacity: 1 block/CU.
//   blocks [0,32):   LSTM scan (round-9 structure) + final release flag=65.
//   blocks [32,256): persistent logits GEMM, m-major tiles (tile=mt*250+nt),
//                    per-mt gate want=min(4mt+5,65); workers poll 32 flags
//                    RELAXED + one acquire fence per gate-change.
// LDS: manual union, 41472 B (scan: 33280+8192; gemm: 2x8192).
// ---------------------------------------------------------------------------
__global__ __launch_bounds__(512) void k_mega(
    const float* __restrict__ Whh, const float* __restrict__ xg,
    const float* __restrict__ h0, const float* __restrict__ c0,
    u16* __restrict__ h_g, u16* __restrict__ A_buf,
    unsigned int* __restrict__ flag,
    const u16* __restrict__ W16, const float* __restrict__ bias,
    float* __restrict__ out)
{
  __shared__ __align__(16) char smem[41472];
  const int tid = threadIdx.x;

  if (blockIdx.x < NBLK_){
    // ======================= SCAN PATH (round-9 verbatim) ==================
    u16 (*hl)[520] = (u16(*)[520])smem;
    float (*gb)[32][16] = (float(*)[32][16])(smem + 33280);
    const int bj = blockIdx.x;
    const int wv = tid >> 6, lane = tid & 63;
    const int g = wv >> 1, m = wv & 1;
    const int lr = lane & 15, lk = lane >> 4;

    bf16x8 bw[16];
    {
      const float* wsrc = Whh + (size_t)(g*H_ + bj*16 + lr)*H_;
      #pragma unroll
      for (int ks = 0; ks < 16; ks++){
        f32x4 w0 = *(const f32x4*)(wsrc + ks*32 + lk*8);
        f32x4 w1 = *(const f32x4*)(wsrc + ks*32 + lk*8 + 4);
        us8 u;
        u[0]=f2b(w0[0]); u[1]=f2b(w0[1]); u[2]=f2b(w0[2]); u[3]=f2b(w0[3]);
        u[4]=f2b(w1[0]); u[5]=f2b(w1[1]); u[6]=f2b(w1[2]); u[7]=f2b(w1[3]);
        bw[ks] = __builtin_bit_cast(bf16x8, u);
      }
    }
    const int ub = tid >> 4, uj = tid & 15;
    float c_reg = c0[ub*H_ + bj*16 + uj];

    {
      int r = tid >> 4, seg = tid & 15;
      const float* src = h0 + r*H_ + seg*32;
      #pragma unroll
      for (int q = 0; q < 4; q++){
        f32x4 v0 = *(const f32x4*)(src + q*8);
        f32x4 v1 = *(const f32x4*)(src + q*8 + 4);
        us8 u;
        u[0]=f2b(v0[0]); u[1]=f2b(v0[1]); u[2]=f2b(v0[2]); u[3]=f2b(v0[3]);
        u[4]=f2b(v1[0]); u[5]=f2b(v1[1]); u[6]=f2b(v1[2]); u[7]=f2b(v1[3]);
        *(us8*)&hl[r][seg*32 + q*8] = u;
      }
    }
    __syncthreads();

    for (int t = 0; t < T_; t++){
      const float* xr = xg + (size_t)t*(B_*G4_) + ub*G4_ + bj*16 + uj;
      float x0 = xr[0*H_], x1 = xr[1*H_], x2 = xr[2*H_], x3 = xr[3*H_];

      f32x4 acc = {0.f, 0.f, 0.f, 0.f};
      #pragma unroll
      for (int ks = 0; ks < 16; ks++){
        bf16x8 a = *(const bf16x8*)&hl[m*16 + lr][ks*32 + lk*8];
        acc = __builtin_amdgcn_mfma_f32_16x16x32_bf16(a, bw[ks], acc, 0, 0, 0);
      }
      #pragma unroll
      for (int i = 0; i < 4; i++)
        gb[g][m*16 + lk*4 + i][lr] = acc[i];
      __syncthreads();

      float gi = sigm(gb[0][ub][uj] + x0);
      float gf = sigm(gb[1][ub][uj] + x1);
      float gg = tanhf(gb[2][ub][uj] + x2);
      float go = sigm(gb[3][ub][uj] + x3);
      c_reg = gf*c_reg + gi*gg;
      float h = go * tanhf(c_reg);
      int p = (t+1) & 1;
      h_g[p*(B_*H_) + bj*(B_*16) + tid] = f2b(h);

      __syncthreads();   // drains h_g stores (vmcnt0) before release
      if (t < T_-1 && tid == 0)
        __hip_atomic_store(&flag[bj*16], (unsigned)(t+1),
                           __ATOMIC_RELEASE, __HIP_MEMORY_SCOPE_AGENT);

      A_buf[(size_t)t*(B_*H_) + ub*H_ + bj*16 + uj] = f2b(tanhf(h));
      if (t == T_-1) break;

      if (tid < 64){
        unsigned want = (unsigned)(t+1), guard = 0;
        while (__hip_atomic_load(&flag[(tid&31)*16], __ATOMIC_ACQUIRE,
                                 __HIP_MEMORY_SCOPE_AGENT) < want
               && guard < (1u<<18)) { __builtin_amdgcn_s_sleep(1); ++guard; }
      }
      __syncthreads();

      {
        int r = tid >> 4, seg = tid & 15;
        const u16* hb = h_g + p*(B_*H_);
        const u16* p0 = hb + (seg*2)  *(B_*16) + r*16;
        const u16* p1 = hb + (seg*2+1)*(B_*16) + r*16;
        us8 v0 = *(const us8*)(p0);
        us8 v1 = *(const us8*)(p0 + 8);
        us8 v2 = *(const us8*)(p1);
        us8 v3 = *(const us8*)(p1 + 8);
        *(us8*)&hl[r][seg*32]      = v0;
        *(us8*)&hl[r][seg*32 + 8]  = v1;
        *(us8*)&hl[r][seg*32 + 16] = v2;
        *(us8*)&hl[r][seg*32 + 24] = v3;
      }
      __syncthreads();
    }
    // final publish: A of t=63 (and all prior) flushed by this release
    __syncthreads();   // drain last A_buf stores
    if (tid == 0)
      __hip_atomic_store(&flag[bj*16], 65u,
                         __ATOMIC_RELEASE, __HIP_MEMORY_SCOPE_AGENT);
  } else {
    // =============== GEMM PATH (512-thread decomposition, m-major) ========
    u16* As = (u16*)smem;
    u16* Bs = (u16*)(smem + 8192);
    const int w = tid>>6, lane = tid&63;
    const int wr = w & 1, wc = w >> 1;               // 2 x 4 wave grid
    const int lr = lane&15, lk = lane>>4;
    const int srow = w*16 + (lane>>2);               // 0..127
    const int cb   = ((lane&3)*16) ^ (((srow>>1)&3)<<4);
    u16* adst = &As[(w*16)*32];                      // wave rows [w*16,w*16+16)
    u16* bdst = &Bs[(w*16)*32];

    int prev_want = -1;
    for (int tile = (int)blockIdx.x - NBLK_; tile < NM_TILES*NT_TILES; tile += NG_){
      const int mt = tile / NT_TILES;       // non-decreasing per block
      const int nt = tile - mt*NT_TILES;    // 0..249
      const int bm0 = mt*128, bn0 = nt*128;
      const unsigned want = (mt < 15) ? (unsigned)(4*mt + 5) : 65u;
      if ((int)want != prev_want){
        if (tid < 64){
          unsigned guard = 0;
          for (;;){
            unsigned v = __hip_atomic_load(&flag[(tid&31)*16], __ATOMIC_RELAXED,
                                           __HIP_MEMORY_SCOPE_AGENT);
            if (__all(v >= want) || guard > (1u<<20)) break;
            __builtin_amdgcn_s_sleep(8); ++guard;
          }
          __builtin_amdgcn_fence(__ATOMIC_ACQUIRE, "agent");  // one inv/gate
        }
        prev_want = (int)want;
      }
      __syncthreads();   // all threads: wait done + LDS free

      const u16* aptr = A_buf + (size_t)(bm0+srow)*H_ + (cb>>1);
      const u16* bptr = W16   + (size_t)(bn0+srow)*H_ + (cb>>1);
      f32x4 acc[4][2] = {};
      for (int k0 = 0; k0 < H_; k0 += 32){
        gload16(aptr + k0, adst);
        gload16(bptr + k0, bdst);
        __syncthreads();
        bf16x8 af[4], bfr[2];
        #pragma unroll
        for (int m = 0; m < 4; m++){
          int row = wr*64 + m*16 + lr;
          af[m] = *(const bf16x8*)((const char*)As + row*64 + ((lk*16) ^ (((row>>1)&3)<<4)));
        }
        #pragma unroll
        for (int n = 0; n < 2; n++){
          int row = wc*32 + n*16 + lr;
          bfr[n] = *(const bf16x8*)((const char*)Bs + row*64 + ((lk*16) ^ (((row>>1)&3)<<4)));
        }
        #pragma unroll
        for (int m = 0; m < 4; m++)
          #pragma unroll
          for (int n = 0; n < 2; n++)
            acc[m][n] = __builtin_amdgcn_mfma_f32_16x16x32_bf16(af[m], bfr[n], acc[m][n], 0, 0, 0);
        __syncthreads();
      }
      #pragma unroll
      for (int n = 0; n < 2; n++){
        int col = bn0 + wc*32 + n*16 + lr;
        float bv = bias[col];
        #pragma unroll
        for (int m = 0; m < 4; m++){
          #pragma unroll
          for (int i = 0; i < 4; i++){
            int row = bm0 + wr*64 + m*16 + lk*4 + i;
            int t = row>>5, b = row&31;
            __builtin_nontemporal_store(acc[m][n][i] + bv,
                &out[(size_t)b*((size_t)T_*V_) + (size_t)t*V_ + col]);
          }
        }
      }
    }
  }
}

// ---------------------------------------------------------------------------
// Standalone fallback kernels (round-9 proven, 499us total path).
// ---------------------------------------------------------------------------
__global__ __launch_bounds__(512) void k_scan(
    const float* __restrict__ Whh, const float* __restrict__ xg,
    const float* __restrict__ h0, const float* __restrict__ c0,
    u16* __restrict__ h_g, u16* __restrict__ A_buf,
    unsigned int* __restrict__ flag)
{
  __shared__ u16 hl[32][520];
  __shared__ float gb[4][32][16];
  const int bj = blockIdx.x;
  const int tid = threadIdx.x;
  const int wv = tid >> 6, lane = tid & 63;
  const int g = wv >> 1, m = wv & 1;
  const int lr = lane & 15, lk = lane >> 4;
  bf16x8 bw[16];
  {
    const float* wsrc = Whh + (size_t)(g*H_ + bj*16 + lr)*H_;
    #pragma unroll
    for (int ks = 0; ks < 16; ks++){
      f32x4 w0 = *(const f32x4*)(wsrc + ks*32 + lk*8);
      f32x4 w1 = *(const f32x4*)(wsrc + ks*32 + lk*8 + 4);
      us8 u;
      u[0]=f2b(w0[0]); u[1]=f2b(w0[1]); u[2]=f2b(w0[2]); u[3]=f2b(w0[3]);
      u[4]=f2b(w1[0]); u[5]=f2b(w1[1]); u[6]=f2b(w1[2]); u[7]=f2b(w1[3]);
      bw[ks] = __builtin_bit_cast(bf16x8, u);
    }
  }
  const int ub = tid >> 4, uj = tid & 15;
  float c_reg = c0[ub*H_ + bj*16 + uj];
  {
    int r = tid >> 4, seg = tid & 15;
    const float* src = h0 + r*H_ + seg*32;
    #pragma unroll
    for (int q = 0; q < 4; q++){
      f32x4 v0 = *(const f32x4*)(src + q*8);
      f32x4 v1 = *(const f32x4*)(src + q*8 + 4);
      us8 u;
      u[0]=f2b(v0[0]); u[1]=f2b(v0[1]); u[2]=f2b(v0[2]); u[3]=f2b(v0[3]);
      u[4]=f2b(v1[0]); u[5]=f2b(v1[1]); u[6]=f2b(v1[2]); u[7]=f2b(v1[3]);
      *(us8*)&hl[r][seg*32 + q*8] = u;
    }
  }
  __syncthreads();
  for (int t = 0; t < T_; t++){
    const float* xr = xg + (size_t)t*(B_*G4_) + ub*G4_ + bj*16 + uj;
    float x0 = xr[0*H_], x1 = xr[1*H_], x2 = xr[2*H_], x3 = xr[3*H_];
    f32x4 acc = {0.f, 0.f, 0.f, 0.f};
    #pragma unroll
    for (int ks = 0; ks < 16; ks++){
      bf16x8 a = *(const bf16x8*)&hl[m*16 + lr][ks*32 + lk*8];
      acc = __builtin_amdgcn_mfma_f32_16x16x32_bf16(a, bw[ks], acc, 0, 0, 0);
    }
    #pragma unroll
    for (int i = 0; i < 4; i++)
      gb[g][m*16 + lk*4 + i][lr] = acc[i];
    __syncthreads();
    float gi = sigm(gb[0][ub][uj] + x0);
    float gf = sigm(gb[1][ub][uj] + x1);
    float gg = tanhf(gb[2][ub][uj] + x2);
    float go = sigm(gb[3][ub][uj] + x3);
    c_reg = gf*c_reg + gi*gg;
    float h = go * tanhf(c_reg);
    int p = (t+1) & 1;
    h_g[p*(B_*H_) + bj*(B_*16) + tid] = f2b(h);
    __syncthreads();
    if (t < T_-1 && tid == 0)
      __hip_atomic_store(&flag[bj*16], (unsigned)(t+1),
                         __ATOMIC_RELEASE, __HIP_MEMORY_SCOPE_AGENT);
    A_buf[(size_t)t*(B_*H_) + ub*H_ + bj*16 + uj] = f2b(tanhf(h));
    if (t == T_-1) break;
    if (tid < 64){
      unsigned want = (unsigned)(t+1), guard = 0;
      while (__hip_atomic_load(&flag[(tid&31)*16], __ATOMIC_ACQUIRE,
                               __HIP_MEMORY_SCOPE_AGENT) < want
             && guard < (1u<<18)) { __builtin_amdgcn_s_sleep(1); ++guard; }
    }
    __syncthreads();
    {
      int r = tid >> 4, seg = tid & 15;
      const u16* hb = h_g + p*(B_*H_);
      const u16* p0 = hb + (seg*2)  *(B_*16) + r*16;
      const u16* p1 = hb + (seg*2+1)*(B_*16) + r*16;
      us8 v0 = *(const us8*)(p0);
      us8 v1 = *(const us8*)(p0 + 8);
      us8 v2 = *(const us8*)(p1);
      us8 v3 = *(const us8*)(p1 + 8);
      *(us8*)&hl[r][seg*32]      = v0;
      *(us8*)&hl[r][seg*32 + 8]  = v1;
      *(us8*)&hl[r][seg*32 + 16] = v2;
      *(us8*)&hl[r][seg*32 + 24] = v3;
    }
    __syncthreads();
  }
}

__global__ __launch_bounds__(256) void k_logits16(
    const u16* __restrict__ A, const u16* __restrict__ W16,
    const float* __restrict__ bias, float* __restrict__ out)
{
  __shared__ u16 As[128*32];
  __shared__ u16 Bs[128*32];
  int bid = blockIdx.y*16 + blockIdx.x;      // 0..3999
  int nbid = (bid & 7)*500 + (bid >> 3);     // bijective (4000 = 8*500)
  const int bm0 = (nbid & 15)*128;
  const int bn0 = (nbid >> 4)*128;
  const int tid = threadIdx.x;
  const int w = tid>>6, lane = tid&63;
  const int wr = w>>1, wc = w&1, lr = lane&15, lk = lane>>4;
  const int srow = w*32 + (lane>>2);
  const int cb   = ((lane&3)*16) ^ (((srow>>1)&3)<<4);
  const u16* aptr = A   + (size_t)(bm0+srow)*H_ + (cb>>1);
  const u16* bptr = W16 + (size_t)(bn0+srow)*H_ + (cb>>1);
  u16* adst0 = &As[(w*32)*32];
  u16* adst1 = &As[(w*32+16)*32];
  u16* bdst0 = &Bs[(w*32)*32];
  u16* bdst1 = &Bs[(w*32+16)*32];
  f32x4 acc[4][4] = {};
  for (int k0 = 0; k0 < H_; k0 += 32){
    gload16(aptr + k0,          adst0);
    gload16(aptr + k0 + 16*H_,  adst1);
    gload16(bptr + k0,          bdst0);
    gload16(bptr + k0 + 16*H_,  bdst1);
    __syncthreads();
    bf16x8 af[4], bfr[4];
    #pragma unroll
    for (int m = 0; m < 4; m++){
      int row = wr*64 + m*16 + lr;
      af[m] = *(const bf16x8*)((const char*)As + row*64 + ((lk*16) ^ (((row>>1)&3)<<4)));
    }
    #pragma unroll
    for (int n = 0; n < 4; n++){
      int row = wc*64 + n*16 + lr;
      bfr[n] = *(const bf16x8*)((const char*)Bs + row*64 + ((lk*16) ^ (((row>>1)&3)<<4)));
    }
    #pragma unroll
    for (int m = 0; m < 4; m++)
      #pragma unroll
      for (int n = 0; n < 4; n++)
        acc[m][n] = __builtin_amdgcn_mfma_f32_16x16x32_bf16(af[m], bfr[n], acc[m][n], 0, 0, 0);
    __syncthreads();
  }
  #pragma unroll
  for (int n = 0; n < 4; n++){
    int col = bn0 + wc*64 + n*16 + lr;
    float bv = bias[col];
    #pragma unroll
    for (int m = 0; m < 4; m++){
      #pragma unroll
      for (int i = 0; i < 4; i++){
        int row = bm0 + wr*64 + m*16 + lk*4 + i;
        int t = row>>5, b = row&31;
        __builtin_nontemporal_store(acc[m][n][i] + bv,
            &out[(size_t)b*((size_t)T_*V_) + (size_t)t*V_ + col]);
      }
    }
  }
}

__global__ __launch_bounds__(256) void k_logits(
    const u16* __restrict__ A, const float* __restrict__ W,
    const float* __restrict__ bias, float* __restrict__ out)
{
  __shared__ u16 As[128][40];
  __shared__ u16 Bs[128][40];
  const int bm0 = blockIdx.x*128, bn0 = blockIdx.y*128;
  const int tid = threadIdx.x;
  const int w = tid>>6, lane = tid&63;
  const int wr = w>>1, wc = w&1, lr = lane&15, lk = lane>>4;
  const int srow = tid>>1, half = tid&1;
  const u16*   arow = A + (size_t)(bm0+srow)*H_;
  const float* brow = W + (size_t)(bn0+srow)*H_;
  f32x4 acc[4][4] = {};
  for (int k0 = 0; k0 < H_; k0 += 32){
    us8 a0 = *(const us8*)(arow + k0 + half*16);
    us8 a1 = *(const us8*)(arow + k0 + half*16 + 8);
    f32x4 b0 = *(const f32x4*)(brow + k0 + half*16);
    f32x4 b1 = *(const f32x4*)(brow + k0 + half*16 + 4);
    f32x4 b2 = *(const f32x4*)(brow + k0 + half*16 + 8);
    f32x4 b3 = *(const f32x4*)(brow + k0 + half*16 + 12);
    *(us8*)&As[srow][half*16]   = a0;
    *(us8*)&As[srow][half*16+8] = a1;
    us8 vb0, vb1;
    vb0[0]=f2b(b0[0]); vb0[1]=f2b(b0[1]); vb0[2]=f2b(b0[2]); vb0[3]=f2b(b0[3]);
    vb0[4]=f2b(b1[0]); vb0[5]=f2b(b1[1]); vb0[6]=f2b(b1[2]); vb0[7]=f2b(b1[3]);
    vb1[0]=f2b(b2[0]); vb1[1]=f2b(b2[1]); vb1[2]=f2b(b2[2]); vb1[3]=f2b(b2[3]);
    vb1[4]=f2b(b3[0]); vb1[5]=f2b(b3[1]); vb1[6]=f2b(b3[2]); vb1[7]=f2b(b3[3]);
    *(us8*)&Bs[srow][half*16]   = vb0;
    *(us8*)&Bs[srow][half*16+8] = vb1;
    __syncthreads();
    bf16x8 af[4], bfr[4];
    #pragma unroll
    for (int m = 0; m < 4; m++) af[m] = *(const bf16x8*)&As[wr*64 + m*16 + lr][lk*8];
    #pragma unroll
    for (int n = 0; n < 4; n++) bfr[n] = *(const bf16x8*)&Bs[wc*64 + n*16 + lr][lk*8];
    #pragma unroll
    for (int m = 0; m < 4; m++)
      #pragma unroll
      for (int n = 0; n < 4; n++)
        acc[m][n] = __builtin_amdgcn_mfma_f32_16x16x32_bf16(af[m], bfr[n], acc[m][n], 0, 0, 0);
    __syncthreads();
  }
  #pragma unroll
  for (int n = 0; n < 4; n++){
    int col = bn0 + wc*64 + n*16 + lr;
    float bv = bias[col];
    #pragma unroll
    for (int m = 0; m < 4; m++){
      #pragma unroll
      for (int i = 0; i < 4; i++){
        int row = bm0 + wr*64 + m*16 + lk*4 + i;
        int t = row>>5, b = row&31;
        out[(size_t)b*((size_t)T_*V_) + (size_t)t*V_ + col] = acc[m][n][i] + bv;
      }
    }
  }
}

// ---------------------------------------------------------------------------
extern "C" void kernel_launch(void* const* d_in, const int* in_sizes, int n_in,
                              void* d_out, int out_size, void* d_ws, size_t ws_size,
                              hipStream_t stream)
{
  const int*   trg    = (const int*)d_in[0];
  const float* init_h = (const float*)d_in[1];
  const float* init_c = (const float*)d_in[2];
  const float* emb    = (const float*)d_in[3];
  const float* Wh     = (const float*)d_in[4];
  const float* bh     = (const float*)d_in[5];
  const float* Wc     = (const float*)d_in[6];
  const float* bc     = (const float*)d_in[7];
  const float* Wih    = (const float*)d_in[8];
  const float* Whh    = (const float*)d_in[9];
  const float* bih    = (const float*)d_in[10];
  const float* bhh    = (const float*)d_in[11];
  const float* Wlogit = (const float*)d_in[12];
  const float* blogit = (const float*)d_in[13];
  float* out = (float*)d_out;

  // workspace layout (bytes)
  char* ws = (char*)d_ws;
  float*        xg    = (float*)(ws);               // 16,777,216
  float*        h0    = (float*)(ws + 16777216);    //     65,536
  float*        c0    = (float*)(ws + 16842752);    //     65,536
  u16*          A_buf = (u16*)  (ws + 16908288);    //  2,097,152
  u16*          h_g   = (u16*)  (ws + 19005440);    //    131,072 (2 parities)
  unsigned int* flag  = (unsigned int*)(ws + 19136512); // 2,048 (32 x 64B)
  u16*          W16   = (u16*)  (ws + 19138560);    // 32,768,000 (optional)
  const size_t need_w16 = 19138560ull + 32768000ull;
  const bool use_w16 = (ws_size >= need_w16);

  hipLaunchKernelGGL(k_init, dim3(128), dim3(256), 0, stream,
                     init_h, init_c, Wh, bh, Wc, bc, h0, c0, flag);
  if (use_w16)
    hipLaunchKernelGGL(k_cvt, dim3((V_*H_)/(256*8)), dim3(256), 0, stream,
                       Wlogit, W16);
  hipLaunchKernelGGL(k_xgates, dim3(16, 16), dim3(256), 0, stream,
                     emb, Wih, trg, bih, bhh, xg);
  if (use_w16){
    void* args[] = { (void*)&Whh, (void*)&xg, (void*)&h0, (void*)&c0,
                     (void*)&h_g, (void*)&A_buf, (void*)&flag,
                     (void*)&W16, (void*)&blogit, (void*)&out };
    hipError_t merr = hipLaunchCooperativeKernel((void*)k_mega,
                          dim3(NBLK_ + NG_), dim3(512), args, 0, stream);
    if (merr != hipSuccess){
      // fallback: proven round-9 pipeline (deterministic: capacity is static)
      void* sargs[] = { (void*)&Whh, (void*)&xg, (void*)&h0, (void*)&c0,
                        (void*)&h_g, (void*)&A_buf, (void*)&flag };
      hipLaunchCooperativeKernel((void*)k_scan, dim3(NBLK_), dim3(512),
                                 sargs, 0, stream);
      hipLaunchKernelGGL(k_logits16, dim3(16, 250), dim3(256), 0, stream,
                         A_buf, W16, blogit, out);
    }
  } else {
    void* args[] = { (void*)&Whh, (void*)&xg, (void*)&h0, (void*)&c0,
                     (void*)&h_g, (void*)&A_buf, (void*)&flag };
    hipLaunchCooperativeKernel((void*)k_scan, dim3(NBLK_), dim3(512), args, 0, stream);
    hipLaunchKernelGGL(k_logits, dim3(16, 250), dim3(256), 0, stream,
                       A_buf, Wlogit, blogit, out);
  }
}

// Round 20
// 439.513 us; speedup vs baseline: 1.9466x; 1.0319x over previous
//
#include <hip/hip_runtime.h>
#include <hip/hip_cooperative_groups.h>

typedef unsigned short u16;
typedef __attribute__((ext_vector_type(8))) unsigned short us8;
typedef __attribute__((ext_vector_type(8))) __bf16 bf16x8;
typedef __attribute__((ext_vector_type(4))) float f32x4;

#define B_ 32
#define T_ 64
#define V_ 32000
#define E_ 300
#define H_ 512
#define G4_ 2048   // 4*H
#define NBLK_ 32   // scan blocks
#define NG_   224  // gemm blocks in mega kernel (total 256 = guaranteed capacity)
#define NT_TILES 250
#define NM_TILES 16

__device__ __forceinline__ u16 f2b(float f){
  unsigned int x = __builtin_bit_cast(unsigned int, f);
  unsigned int r = (x + 0x7FFFu + ((x >> 16) & 1u)) >> 16;
  return (u16)r;
}
__device__ __forceinline__ float sigm(float x){ return 1.0f/(1.0f+expf(-x)); }

__device__ __forceinline__ void gload16(const u16* g, u16* l){
  __builtin_amdgcn_global_load_lds(
      (const __attribute__((address_space(1))) void*)g,
      (__attribute__((address_space(3))) void*)l, 16, 0, 0);
}

// ---------------------------------------------------------------------------
// Kernel 1: h0 = init_h[0] @ Wh^T + bh ; c0 = init_c[0] @ Wc^T + bc   (f32)
// Also zeroes the 32 scan barrier flags (padded 64B apart) every call.
// ---------------------------------------------------------------------------
__global__ __launch_bounds__(256) void k_init(
    const float* __restrict__ init_h, const float* __restrict__ init_c,
    const float* __restrict__ Wh, const float* __restrict__ bh,
    const float* __restrict__ Wc, const float* __restrict__ bc,
    float* __restrict__ h0out, float* __restrict__ c0out,
    unsigned int* __restrict__ flag)
{
  if (blockIdx.x == 0){ flag[threadIdx.x] = 0u; flag[threadIdx.x + 256] = 0u; }
  int idx = blockIdx.x*blockDim.x + threadIdx.x;    // 0..32767
  int sel = idx >> 14;                              // 0: h, 1: c
  int r = idx & 16383;
  int b = r >> 9, j = r & 511;
  const float* x = (sel ? init_c : init_h) + b*H_;
  const float* w = (sel ? Wc : Wh) + (size_t)j*H_;
  const float* bias = sel ? bc : bh;
  float acc = 0.f;
  for (int k = 0; k < H_; k += 8){
    f32x4 x0 = *(const f32x4*)(x + k), x1 = *(const f32x4*)(x + k + 4);
    f32x4 w0 = *(const f32x4*)(w + k), w1 = *(const f32x4*)(w + k + 4);
    acc += x0[0]*w0[0] + x0[1]*w0[1] + x0[2]*w0[2] + x0[3]*w0[3];
    acc += x1[0]*w1[0] + x1[1]*w1[1] + x1[2]*w1[2] + x1[3]*w1[3];
  }
  acc += bias[j];
  (sel ? c0out : h0out)[b*H_ + j] = acc;
}

// ---------------------------------------------------------------------------
// Kernel 1b: W_logit f32 -> bf16 prepass (16.384M elems, 8/thread, exact grid)
// ---------------------------------------------------------------------------
__global__ __launch_bounds__(256) void k_cvt(
    const float* __restrict__ W, u16* __restrict__ W16)
{
  size_t i = ((size_t)blockIdx.x*256 + threadIdx.x)*8;
  f32x4 a = *(const f32x4*)(W + i);
  f32x4 b = *(const f32x4*)(W + i + 4);
  us8 u;
  u[0]=f2b(a[0]); u[1]=f2b(a[1]); u[2]=f2b(a[2]); u[3]=f2b(a[3]);
  u[4]=f2b(b[0]); u[5]=f2b(b[1]); u[6]=f2b(b[2]); u[7]=f2b(b[3]);
  *(us8*)(W16 + i) = u;
}

// ---------------------------------------------------------------------------
// Kernel 2: xg[t][b][g] = emb[token(b,t)] . W_ih[g] + b_ih[g] + b_hh[g]  (f32)
// MFMA GEMM, M=2048 (rows r=t*32+b gathered from embedding), N=2048, K=300.
// ---------------------------------------------------------------------------
__global__ __launch_bounds__(256) void k_xgates(
    const float* __restrict__ emb, const float* __restrict__ Wih,
    const int* __restrict__ trg, const float* __restrict__ bih,
    const float* __restrict__ bhh, float* __restrict__ xg)
{
  __shared__ u16 As[128][40];   // +8 pad: row stride 80B -> conflict-free b128
  __shared__ u16 Bs[128][40];
  const int bn0 = blockIdx.x*128, bm0 = blockIdx.y*128;
  const int tid = threadIdx.x;
  const int w = tid>>6, lane = tid&63;
  const int wr = w>>1, wc = w&1, lr = lane&15, lk = lane>>4;
  const int srow = tid>>1, half = tid&1;
  const int R = bm0 + srow;
  const int tt = R>>5, bb = R&31;
  const int token = trg[bb*T_ + tt];
  const float* arow = emb + (size_t)token*E_;
  const float* brow = Wih + (size_t)(bn0+srow)*E_;
  f32x4 acc[4][4] = {};
  for (int k0 = 0; k0 < E_; k0 += 32){
    int cbase = k0 + half*16;
    if (k0 + 32 <= E_){
      f32x4 a0=*(const f32x4*)(arow+cbase),    a1=*(const f32x4*)(arow+cbase+4);
      f32x4 a2=*(const f32x4*)(arow+cbase+8),  a3=*(const f32x4*)(arow+cbase+12);
      f32x4 b0=*(const f32x4*)(brow+cbase),    b1=*(const f32x4*)(brow+cbase+4);
      f32x4 b2=*(const f32x4*)(brow+cbase+8),  b3=*(const f32x4*)(brow+cbase+12);
      us8 ua, ub;
      ua[0]=f2b(a0[0]); ua[1]=f2b(a0[1]); ua[2]=f2b(a0[2]); ua[3]=f2b(a0[3]);
      ua[4]=f2b(a1[0]); ua[5]=f2b(a1[1]); ua[6]=f2b(a1[2]); ua[7]=f2b(a1[3]);
      ub[0]=f2b(a2[0]); ub[1]=f2b(a2[1]); ub[2]=f2b(a2[2]); ub[3]=f2b(a2[3]);
      ub[4]=f2b(a3[0]); ub[5]=f2b(a3[1]); ub[6]=f2b(a3[2]); ub[7]=f2b(a3[3]);
      *(us8*)&As[srow][half*16]   = ua;
      *(us8*)&As[srow][half*16+8] = ub;
      us8 va, vb;
      va[0]=f2b(b0[0]); va[1]=f2b(b0[1]); va[2]=f2b(b0[2]); va[3]=f2b(b0[3]);
      va[4]=f2b(b1[0]); va[5]=f2b(b1[1]); va[6]=f2b(b1[2]); va[7]=f2b(b1[3]);
      vb[0]=f2b(b2[0]); vb[1]=f2b(b2[1]); vb[2]=f2b(b2[2]); vb[3]=f2b(b2[3]);
      vb[4]=f2b(b3[0]); vb[5]=f2b(b3[1]); vb[6]=f2b(b3[2]); vb[7]=f2b(b3[3]);
      *(us8*)&Bs[srow][half*16]   = va;
      *(us8*)&Bs[srow][half*16+8] = vb;
    } else {
      for (int i = 0; i < 16; i++){
        int c = cbase + i;
        As[srow][half*16+i] = (c < E_) ? f2b(arow[c]) : (u16)0;
        Bs[srow][half*16+i] = (c < E_) ? f2b(brow[c]) : (u16)0;
      }
    }
    __syncthreads();
    bf16x8 af[4], bfr[4];
    #pragma unroll
    for (int m = 0; m < 4; m++) af[m] = *(const bf16x8*)&As[wr*64 + m*16 + lr][lk*8];
    #pragma unroll
    for (int n = 0; n < 4; n++) bfr[n] = *(const bf16x8*)&Bs[wc*64 + n*16 + lr][lk*8];
    #pragma unroll
    for (int m = 0; m < 4; m++)
      #pragma unroll
      for (int n = 0; n < 4; n++)
        acc[m][n] = __builtin_amdgcn_mfma_f32_16x16x32_bf16(af[m], bfr[n], acc[m][n], 0, 0, 0);
    __syncthreads();
  }
  #pragma unroll
  for (int n = 0; n < 4; n++){
    int col = bn0 + wc*64 + n*16 + lr;
    float bv = bih[col] + bhh[col];
    #pragma unroll
    for (int m = 0; m < 4; m++){
      #pragma unroll
      for (int i = 0; i < 4; i++){
        int row = bm0 + wr*64 + m*16 + lk*4 + i;
        xg[(size_t)row*G4_ + col] = acc[m][n][i] + bv;
      }
    }
  }
}

// ---------------------------------------------------------------------------
// Mega kernel (cooperative, 256 blocks x 512 thr). R19 structure; worker
// k-loop widened BK 32->64: 8 k-iters with ONE vmcnt-drain barrier each
// (R19: 16 iters -> 19us/tile, latency-bound on the drain; compute bound is
// 0.44us). LDS 2x16KB. Swizzle for 128B rows: LDS chunk c of row holds
// global chunk c^(row&7) (bits 4-6, in-row involution); reads 2-way banked.
//   blocks [0,32):   LSTM scan (round-9 structure) + final release flag=65.
//   blocks [32,256): persistent logits GEMM, m-major tiles, per-mt gate
//                    want=min(4mt+5,65); RELAXED polls + 1 fence/gate.
// ---------------------------------------------------------------------------
__global__ __launch_bounds__(512) void k_mega(
    const float* __restrict__ Whh, const float* __restrict__ xg,
    const float* __restrict__ h0, const float* __restrict__ c0,
    u16* __restrict__ h_g, u16* __restrict__ A_buf,
    unsigned int* __restrict__ flag,
    const u16* __restrict__ W16, const float* __restrict__ bias,
    float* __restrict__ out)
{
  __shared__ __align__(16) char smem[41472];
  const int tid = threadIdx.x;

  if (blockIdx.x < NBLK_){
    // ======================= SCAN PATH (round-9 verbatim) ==================
    u16 (*hl)[520] = (u16(*)[520])smem;
    float (*gb)[32][16] = (float(*)[32][16])(smem + 33280);
    const int bj = blockIdx.x;
    const int wv = tid >> 6, lane = tid & 63;
    const int g = wv >> 1, m = wv & 1;
    const int lr = lane & 15, lk = lane >> 4;

    bf16x8 bw[16];
    {
      const float* wsrc = Whh + (size_t)(g*H_ + bj*16 + lr)*H_;
      #pragma unroll
      for (int ks = 0; ks < 16; ks++){
        f32x4 w0 = *(const f32x4*)(wsrc + ks*32 + lk*8);
        f32x4 w1 = *(const f32x4*)(wsrc + ks*32 + lk*8 + 4);
        us8 u;
        u[0]=f2b(w0[0]); u[1]=f2b(w0[1]); u[2]=f2b(w0[2]); u[3]=f2b(w0[3]);
        u[4]=f2b(w1[0]); u[5]=f2b(w1[1]); u[6]=f2b(w1[2]); u[7]=f2b(w1[3]);
        bw[ks] = __builtin_bit_cast(bf16x8, u);
      }
    }
    const int ub = tid >> 4, uj = tid & 15;
    float c_reg = c0[ub*H_ + bj*16 + uj];

    {
      int r = tid >> 4, seg = tid & 15;
      const float* src = h0 + r*H_ + seg*32;
      #pragma unroll
      for (int q = 0; q < 4; q++){
        f32x4 v0 = *(const f32x4*)(src + q*8);
        f32x4 v1 = *(const f32x4*)(src + q*8 + 4);
        us8 u;
        u[0]=f2b(v0[0]); u[1]=f2b(v0[1]); u[2]=f2b(v0[2]); u[3]=f2b(v0[3]);
        u[4]=f2b(v1[0]); u[5]=f2b(v1[1]); u[6]=f2b(v1[2]); u[7]=f2b(v1[3]);
        *(us8*)&hl[r][seg*32 + q*8] = u;
      }
    }
    __syncthreads();

    for (int t = 0; t < T_; t++){
      const float* xr = xg + (size_t)t*(B_*G4_) + ub*G4_ + bj*16 + uj;
      float x0 = xr[0*H_], x1 = xr[1*H_], x2 = xr[2*H_], x3 = xr[3*H_];

      f32x4 acc = {0.f, 0.f, 0.f, 0.f};
      #pragma unroll
      for (int ks = 0; ks < 16; ks++){
        bf16x8 a = *(const bf16x8*)&hl[m*16 + lr][ks*32 + lk*8];
        acc = __builtin_amdgcn_mfma_f32_16x16x32_bf16(a, bw[ks], acc, 0, 0, 0);
      }
      #pragma unroll
      for (int i = 0; i < 4; i++)
        gb[g][m*16 + lk*4 + i][lr] = acc[i];
      __syncthreads();

      float gi = sigm(gb[0][ub][uj] + x0);
      float gf = sigm(gb[1][ub][uj] + x1);
      float gg = tanhf(gb[2][ub][uj] + x2);
      float go = sigm(gb[3][ub][uj] + x3);
      c_reg = gf*c_reg + gi*gg;
      float h = go * tanhf(c_reg);
      int p = (t+1) & 1;
      h_g[p*(B_*H_) + bj*(B_*16) + tid] = f2b(h);

      __syncthreads();   // drains h_g stores (vmcnt0) before release
      if (t < T_-1 && tid == 0)
        __hip_atomic_store(&flag[bj*16], (unsigned)(t+1),
                           __ATOMIC_RELEASE, __HIP_MEMORY_SCOPE_AGENT);

      A_buf[(size_t)t*(B_*H_) + ub*H_ + bj*16 + uj] = f2b(tanhf(h));
      if (t == T_-1) break;

      if (tid < 64){
        unsigned want = (unsigned)(t+1), guard = 0;
        while (__hip_atomic_load(&flag[(tid&31)*16], __ATOMIC_ACQUIRE,
                                 __HIP_MEMORY_SCOPE_AGENT) < want
               && guard < (1u<<18)) { __builtin_amdgcn_s_sleep(1); ++guard; }
      }
      __syncthreads();

      {
        int r = tid >> 4, seg = tid & 15;
        const u16* hb = h_g + p*(B_*H_);
        const u16* p0 = hb + (seg*2)  *(B_*16) + r*16;
        const u16* p1 = hb + (seg*2+1)*(B_*16) + r*16;
        us8 v0 = *(const us8*)(p0);
        us8 v1 = *(const us8*)(p0 + 8);
        us8 v2 = *(const us8*)(p1);
        us8 v3 = *(const us8*)(p1 + 8);
        *(us8*)&hl[r][seg*32]      = v0;
        *(us8*)&hl[r][seg*32 + 8]  = v1;
        *(us8*)&hl[r][seg*32 + 16] = v2;
        *(us8*)&hl[r][seg*32 + 24] = v3;
      }
      __syncthreads();
    }
    // final publish: A of t=63 (and all prior) flushed by this release
    __syncthreads();   // drain last A_buf stores
    if (tid == 0)
      __hip_atomic_store(&flag[bj*16], 65u,
                         __ATOMIC_RELEASE, __HIP_MEMORY_SCOPE_AGENT);
  } else {
    // =============== GEMM PATH (BK=64, 8 k-iters, m-major) ================
    u16* As = (u16*)smem;             // [128][64] u16, 16 KB
    u16* Bs = (u16*)(smem + 16384);   // [128][64] u16, 16 KB
    const int w = tid>>6, lane = tid&63;
    const int wr = w & 1, wc = w >> 1;               // 2 x 4 wave grid
    const int lr = lane&15, lk = lane>>4;
    // staging: instr j in {0,1} covers rows [j*64 + w*8, j*64 + w*8 + 8)
    const int r0 = w*8 + (lane>>3);                  // rows for instr 0
    const int r1 = 64 + r0;                          // rows for instr 1
    const int c0b = ((lane&7)*16) ^ ((r0&7)<<4);     // swizzled byte-col
    const int c1b = ((lane&7)*16) ^ ((r1&7)<<4);
    u16* adst0 = &As[(w*8)*64];       // HW: base + lane*16B (linear 8 rows)
    u16* adst1 = &As[(64 + w*8)*64];
    u16* bdst0 = &Bs[(w*8)*64];
    u16* bdst1 = &Bs[(64 + w*8)*64];

    int prev_want = -1;
    for (int tile = (int)blockIdx.x - NBLK_; tile < NM_TILES*NT_TILES; tile += NG_){
      const int mt = tile / NT_TILES;       // non-decreasing per block
      const int nt = tile - mt*NT_TILES;    // 0..249
      const int bm0 = mt*128, bn0 = nt*128;
      const unsigned want = (mt < 15) ? (unsigned)(4*mt + 5) : 65u;
      if ((int)want != prev_want){
        if (tid < 64){
          unsigned guard = 0;
          for (;;){
            unsigned v = __hip_atomic_load(&flag[(tid&31)*16], __ATOMIC_RELAXED,
                                           __HIP_MEMORY_SCOPE_AGENT);
            if (__all(v >= want) || guard > (1u<<20)) break;
            __builtin_amdgcn_s_sleep(8); ++guard;
          }
          __builtin_amdgcn_fence(__ATOMIC_ACQUIRE, "agent");  // one inv/gate
        }
        prev_want = (int)want;
      }
      __syncthreads();   // all threads: wait done + LDS free

      const u16* a0p = A_buf + (size_t)(bm0+r0)*H_ + (c0b>>1);
      const u16* a1p = A_buf + (size_t)(bm0+r1)*H_ + (c1b>>1);
      const u16* b0p = W16   + (size_t)(bn0+r0)*H_ + (c0b>>1);
      const u16* b1p = W16   + (size_t)(bn0+r1)*H_ + (c1b>>1);
      f32x4 acc[4][2] = {};
      for (int k0 = 0; k0 < H_; k0 += 64){
        gload16(a0p + k0, adst0);
        gload16(a1p + k0, adst1);
        gload16(b0p + k0, bdst0);
        gload16(b1p + k0, bdst1);
        __syncthreads();
        #pragma unroll
        for (int s = 0; s < 2; s++){
          bf16x8 af[4], bfr[2];
          #pragma unroll
          for (int m = 0; m < 4; m++){
            int row = wr*64 + m*16 + lr;
            af[m] = *(const bf16x8*)((const char*)As + row*128
                       + ((s*64 + lk*16) ^ ((row&7)<<4)));
          }
          #pragma unroll
          for (int n = 0; n < 2; n++){
            int row = wc*32 + n*16 + lr;
            bfr[n] = *(const bf16x8*)((const char*)Bs + row*128
                       + ((s*64 + lk*16) ^ ((row&7)<<4)));
          }
          #pragma unroll
          for (int m = 0; m < 4; m++)
            #pragma unroll
            for (int n = 0; n < 2; n++)
              acc[m][n] = __builtin_amdgcn_mfma_f32_16x16x32_bf16(af[m], bfr[n], acc[m][n], 0, 0, 0);
        }
        __syncthreads();
      }
      #pragma unroll
      for (int n = 0; n < 2; n++){
        int col = bn0 + wc*32 + n*16 + lr;
        float bv = bias[col];
        #pragma unroll
        for (int m = 0; m < 4; m++){
          #pragma unroll
          for (int i = 0; i < 4; i++){
            int row = bm0 + wr*64 + m*16 + lk*4 + i;
            int t = row>>5, b = row&31;
            __builtin_nontemporal_store(acc[m][n][i] + bv,
                &out[(size_t)b*((size_t)T_*V_) + (size_t)t*V_ + col]);
          }
        }
      }
    }
  }
}

// ---------------------------------------------------------------------------
// Standalone fallback kernels (round-9 proven, 499us total path).
// ---------------------------------------------------------------------------
__global__ __launch_bounds__(512) void k_scan(
    const float* __restrict__ Whh, const float* __restrict__ xg,
    const float* __restrict__ h0, const float* __restrict__ c0,
    u16* __restrict__ h_g, u16* __restrict__ A_buf,
    unsigned int* __restrict__ flag)
{
  __shared__ u16 hl[32][520];
  __shared__ float gb[4][32][16];
  const int bj = blockIdx.x;
  const int tid = threadIdx.x;
  const int wv = tid >> 6, lane = tid & 63;
  const int g = wv >> 1, m = wv & 1;
  const int lr = lane & 15, lk = lane >> 4;
  bf16x8 bw[16];
  {
    const float* wsrc = Whh + (size_t)(g*H_ + bj*16 + lr)*H_;
    #pragma unroll
    for (int ks = 0; ks < 16; ks++){
      f32x4 w0 = *(const f32x4*)(wsrc + ks*32 + lk*8);
      f32x4 w1 = *(const f32x4*)(wsrc + ks*32 + lk*8 + 4);
      us8 u;
      u[0]=f2b(w0[0]); u[1]=f2b(w0[1]); u[2]=f2b(w0[2]); u[3]=f2b(w0[3]);
      u[4]=f2b(w1[0]); u[5]=f2b(w1[1]); u[6]=f2b(w1[2]); u[7]=f2b(w1[3]);
      bw[ks] = __builtin_bit_cast(bf16x8, u);
    }
  }
  const int ub = tid >> 4, uj = tid & 15;
  float c_reg = c0[ub*H_ + bj*16 + uj];
  {
    int r = tid >> 4, seg = tid & 15;
    const float* src = h0 + r*H_ + seg*32;
    #pragma unroll
    for (int q = 0; q < 4; q++){
      f32x4 v0 = *(const f32x4*)(src + q*8);
      f32x4 v1 = *(const f32x4*)(src + q*8 + 4);
      us8 u;
      u[0]=f2b(v0[0]); u[1]=f2b(v0[1]); u[2]=f2b(v0[2]); u[3]=f2b(v0[3]);
      u[4]=f2b(v1[0]); u[5]=f2b(v1[1]); u[6]=f2b(v1[2]); u[7]=f2b(v1[3]);
      *(us8*)&hl[r][seg*32 + q*8] = u;
    }
  }
  __syncthreads();
  for (int t = 0; t < T_; t++){
    const float* xr = xg + (size_t)t*(B_*G4_) + ub*G4_ + bj*16 + uj;
    float x0 = xr[0*H_], x1 = xr[1*H_], x2 = xr[2*H_], x3 = xr[3*H_];
    f32x4 acc = {0.f, 0.f, 0.f, 0.f};
    #pragma unroll
    for (int ks = 0; ks < 16; ks++){
      bf16x8 a = *(const bf16x8*)&hl[m*16 + lr][ks*32 + lk*8];
      acc = __builtin_amdgcn_mfma_f32_16x16x32_bf16(a, bw[ks], acc, 0, 0, 0);
    }
    #pragma unroll
    for (int i = 0; i < 4; i++)
      gb[g][m*16 + lk*4 + i][lr] = acc[i];
    __syncthreads();
    float gi = sigm(gb[0][ub][uj] + x0);
    float gf = sigm(gb[1][ub][uj] + x1);
    float gg = tanhf(gb[2][ub][uj] + x2);
    float go = sigm(gb[3][ub][uj] + x3);
    c_reg = gf*c_reg + gi*gg;
    float h = go * tanhf(c_reg);
    int p = (t+1) & 1;
    h_g[p*(B_*H_) + bj*(B_*16) + tid] = f2b(h);
    __syncthreads();
    if (t < T_-1 && tid == 0)
      __hip_atomic_store(&flag[bj*16], (unsigned)(t+1),
                         __ATOMIC_RELEASE, __HIP_MEMORY_SCOPE_AGENT);
    A_buf[(size_t)t*(B_*H_) + ub*H_ + bj*16 + uj] = f2b(tanhf(h));
    if (t == T_-1) break;
    if (tid < 64){
      unsigned want = (unsigned)(t+1), guard = 0;
      while (__hip_atomic_load(&flag[(tid&31)*16], __ATOMIC_ACQUIRE,
                               __HIP_MEMORY_SCOPE_AGENT) < want
             && guard < (1u<<18)) { __builtin_amdgcn_s_sleep(1); ++guard; }
    }
    __syncthreads();
    {
      int r = tid >> 4, seg = tid & 15;
      const u16* hb = h_g + p*(B_*H_);
      const u16* p0 = hb + (seg*2)  *(B_*16) + r*16;
      const u16* p1 = hb + (seg*2+1)*(B_*16) + r*16;
      us8 v0 = *(const us8*)(p0);
      us8 v1 = *(const us8*)(p0 + 8);
      us8 v2 = *(const us8*)(p1);
      us8 v3 = *(const us8*)(p1 + 8);
      *(us8*)&hl[r][seg*32]      = v0;
      *(us8*)&hl[r][seg*32 + 8]  = v1;
      *(us8*)&hl[r][seg*32 + 16] = v2;
      *(us8*)&hl[r][seg*32 + 24] = v3;
    }
    __syncthreads();
  }
}

__global__ __launch_bounds__(256) void k_logits16(
    const u16* __restrict__ A, const u16* __restrict__ W16,
    const float* __restrict__ bias, float* __restrict__ out)
{
  __shared__ u16 As[128*32];
  __shared__ u16 Bs[128*32];
  int bid = blockIdx.y*16 + blockIdx.x;      // 0..3999
  int nbid = (bid & 7)*500 + (bid >> 3);     // bijective (4000 = 8*500)
  const int bm0 = (nbid & 15)*128;
  const int bn0 = (nbid >> 4)*128;
  const int tid = threadIdx.x;
  const int w = tid>>6, lane = tid&63;
  const int wr = w>>1, wc = w&1, lr = lane&15, lk = lane>>4;
  const int srow = w*32 + (lane>>2);
  const int cb   = ((lane&3)*16) ^ (((srow>>1)&3)<<4);
  const u16* aptr = A   + (size_t)(bm0+srow)*H_ + (cb>>1);
  const u16* bptr = W16 + (size_t)(bn0+srow)*H_ + (cb>>1);
  u16* adst0 = &As[(w*32)*32];
  u16* adst1 = &As[(w*32+16)*32];
  u16* bdst0 = &Bs[(w*32)*32];
  u16* bdst1 = &Bs[(w*32+16)*32];
  f32x4 acc[4][4] = {};
  for (int k0 = 0; k0 < H_; k0 += 32){
    gload16(aptr + k0,          adst0);
    gload16(aptr + k0 + 16*H_,  adst1);
    gload16(bptr + k0,          bdst0);
    gload16(bptr + k0 + 16*H_,  bdst1);
    __syncthreads();
    bf16x8 af[4], bfr[4];
    #pragma unroll
    for (int m = 0; m < 4; m++){
      int row = wr*64 + m*16 + lr;
      af[m] = *(const bf16x8*)((const char*)As + row*64 + ((lk*16) ^ (((row>>1)&3)<<4)));
    }
    #pragma unroll
    for (int n = 0; n < 4; n++){
      int row = wc*64 + n*16 + lr;
      bfr[n] = *(const bf16x8*)((const char*)Bs + row*64 + ((lk*16) ^ (((row>>1)&3)<<4)));
    }
    #pragma unroll
    for (int m = 0; m < 4; m++)
      #pragma unroll
      for (int n = 0; n < 4; n++)
        acc[m][n] = __builtin_amdgcn_mfma_f32_16x16x32_bf16(af[m], bfr[n], acc[m][n], 0, 0, 0);
    __syncthreads();
  }
  #pragma unroll
  for (int n = 0; n < 4; n++){
    int col = bn0 + wc*64 + n*16 + lr;
    float bv = bias[col];
    #pragma unroll
    for (int m = 0; m < 4; m++){
      #pragma unroll
      for (int i = 0; i < 4; i++){
        int row = bm0 + wr*64 + m*16 + lk*4 + i;
        int t = row>>5, b = row&31;
        __builtin_nontemporal_store(acc[m][n][i] + bv,
            &out[(size_t)b*((size_t)T_*V_) + (size_t)t*V_ + col]);
      }
    }
  }
}

__global__ __launch_bounds__(256) void k_logits(
    const u16* __restrict__ A, const float* __restrict__ W,
    const float* __restrict__ bias, float* __restrict__ out)
{
  __shared__ u16 As[128][40];
  __shared__ u16 Bs[128][40];
  const int bm0 = blockIdx.x*128, bn0 = blockIdx.y*128;
  const int tid = threadIdx.x;
  const int w = tid>>6, lane = tid&63;
  const int wr = w>>1, wc = w&1, lr = lane&15, lk = lane>>4;
  const int srow = tid>>1, half = tid&1;
  const u16*   arow = A + (size_t)(bm0+srow)*H_;
  const float* brow = W + (size_t)(bn0+srow)*H_;
  f32x4 acc[4][4] = {};
  for (int k0 = 0; k0 < H_; k0 += 32){
    us8 a0 = *(const us8*)(arow + k0 + half*16);
    us8 a1 = *(const us8*)(arow + k0 + half*16 + 8);
    f32x4 b0 = *(const f32x4*)(brow + k0 + half*16);
    f32x4 b1 = *(const f32x4*)(brow + k0 + half*16 + 4);
    f32x4 b2 = *(const f32x4*)(brow + k0 + half*16 + 8);
    f32x4 b3 = *(const f32x4*)(brow + k0 + half*16 + 12);
    *(us8*)&As[srow][half*16]   = a0;
    *(us8*)&As[srow][half*16+8] = a1;
    us8 vb0, vb1;
    vb0[0]=f2b(b0[0]); vb0[1]=f2b(b0[1]); vb0[2]=f2b(b0[2]); vb0[3]=f2b(b0[3]);
    vb0[4]=f2b(b1[0]); vb0[5]=f2b(b1[1]); vb0[6]=f2b(b1[2]); vb0[7]=f2b(b1[3]);
    vb1[0]=f2b(b2[0]); vb1[1]=f2b(b2[1]); vb1[2]=f2b(b2[2]); vb1[3]=f2b(b2[3]);
    vb1[4]=f2b(b3[0]); vb1[5]=f2b(b3[1]); vb1[6]=f2b(b3[2]); vb1[7]=f2b(b3[3]);
    *(us8*)&Bs[srow][half*16]   = vb0;
    *(us8*)&Bs[srow][half*16+8] = vb1;
    __syncthreads();
    bf16x8 af[4], bfr[4];
    #pragma unroll
    for (int m = 0; m < 4; m++) af[m] = *(const bf16x8*)&As[wr*64 + m*16 + lr][lk*8];
    #pragma unroll
    for (int n = 0; n < 4; n++) bfr[n] = *(const bf16x8*)&Bs[wc*64 + n*16 + lr][lk*8];
    #pragma unroll
    for (int m = 0; m < 4; m++)
      #pragma unroll
      for (int n = 0; n < 4; n++)
        acc[m][n] = __builtin_amdgcn_mfma_f32_16x16x32_bf16(af[m], bfr[n], acc[m][n], 0, 0, 0);
    __syncthreads();
  }
  #pragma unroll
  for (int n = 0; n < 4; n++){
    int col = bn0 + wc*64 + n*16 + lr;
    float bv = bias[col];
    #pragma unroll
    for (int m = 0; m < 4; m++){
      #pragma unroll
      for (int i = 0; i < 4; i++){
        int row = bm0 + wr*64 + m*16 + lk*4 + i;
        int t = row>>5, b = row&31;
        out[(size_t)b*((size_t)T_*V_) + (size_t)t*V_ + col] = acc[m][n][i] + bv;
      }
    }
  }
}

// ---------------------------------------------------------------------------
extern "C" void kernel_launch(void* const* d_in, const int* in_sizes, int n_in,
                              void* d_out, int out_size, void* d_ws, size_t ws_size,
                              hipStream_t stream)
{
  const int*   trg    = (const int*)d_in[0];
  const float* init_h = (const float*)d_in[1];
  const float* init_c = (const float*)d_in[2];
  const float* emb    = (const float*)d_in[3];
  const float* Wh     = (const float*)d_in[4];
  const float* bh     = (const float*)d_in[5];
  const float* Wc     = (const float*)d_in[6];
  const float* bc     = (const float*)d_in[7];
  const float* Wih    = (const float*)d_in[8];
  const float* Whh    = (const float*)d_in[9];
  const float* bih    = (const float*)d_in[10];
  const float* bhh    = (const float*)d_in[11];
  const float* Wlogit = (const float*)d_in[12];
  const float* blogit = (const float*)d_in[13];
  float* out = (float*)d_out;

  // workspace layout (bytes)
  char* ws = (char*)d_ws;
  float*        xg    = (float*)(ws);               // 16,777,216
  float*        h0    = (float*)(ws + 16777216);    //     65,536
  float*        c0    = (float*)(ws + 16842752);    //     65,536
  u16*          A_buf = (u16*)  (ws + 16908288);    //  2,097,152
  u16*          h_g   = (u16*)  (ws + 19005440);    //    131,072 (2 parities)
  unsigned int* flag  = (unsigned int*)(ws + 19136512); // 2,048 (32 x 64B)
  u16*          W16   = (u16*)  (ws + 19138560);    // 32,768,000 (optional)
  const size_t need_w16 = 19138560ull + 32768000ull;
  const bool use_w16 = (ws_size >= need_w16);

  hipLaunchKernelGGL(k_init, dim3(128), dim3(256), 0, stream,
                     init_h, init_c, Wh, bh, Wc, bc, h0, c0, flag);
  if (use_w16)
    hipLaunchKernelGGL(k_cvt, dim3((V_*H_)/(256*8)), dim3(256), 0, stream,
                       Wlogit, W16);
  hipLaunchKernelGGL(k_xgates, dim3(16, 16), dim3(256), 0, stream,
                     emb, Wih, trg, bih, bhh, xg);
  if (use_w16){
    void* args[] = { (void*)&Whh, (void*)&xg, (void*)&h0, (void*)&c0,
                     (void*)&h_g, (void*)&A_buf, (void*)&flag,
                     (void*)&W16, (void*)&blogit, (void*)&out };
    hipError_t merr = hipLaunchCooperativeKernel((void*)k_mega,
                          dim3(NBLK_ + NG_), dim3(512), args, 0, stream);
    if (merr != hipSuccess){
      // fallback: proven round-9 pipeline (deterministic: capacity is static)
      void* sargs[] = { (void*)&Whh, (void*)&xg, (void*)&h0, (void*)&c0,
                        (void*)&h_g, (void*)&A_buf, (void*)&flag };
      hipLaunchCooperativeKernel((void*)k_scan, dim3(NBLK_), dim3(512),
                                 sargs, 0, stream);
      hipLaunchKernelGGL(k_logits16, dim3(16, 250), dim3(256), 0, stream,
                         A_buf, W16, blogit, out);
    }
  } else {
    void* args[] = { (void*)&Whh, (void*)&xg, (void*)&h0, (void*)&c0,
                     (void*)&h_g, (void*)&A_buf, (void*)&flag };
    hipLaunchCooperativeKernel((void*)k_scan, dim3(NBLK_), dim3(512), args, 0, stream);
    hipLaunchKernelGGL(k_logits, dim3(16, 250), dim3(256), 0, stream,
                       A_buf, Wlogit, blogit, out);
  }
}

// Round 21
// 434.326 us; speedup vs baseline: 1.9698x; 1.0119x over previous
//
#include <hip/hip_runtime.h>
#include <hip/hip_cooperative_groups.h>

typedef unsigned short u16;
typedef __attribute__((ext_vector_type(8))) unsigned short us8;
typedef __attribute__((ext_vector_type(8))) __bf16 bf16x8;
typedef __attribute__((ext_vector_type(4))) float f32x4;

#define B_ 32
#define T_ 64
#define V_ 32000
#define E_ 300
#define H_ 512
#define G4_ 2048   // 4*H
#define NBLK_ 32   // scan blocks
#define NG_   224  // gemm blocks in mega kernel (total 256 = guaranteed capacity)
#define NT_TILES 250
#define NM_TILES 16

__device__ __forceinline__ u16 f2b(float f){
  unsigned int x = __builtin_bit_cast(unsigned int, f);
  unsigned int r = (x + 0x7FFFu + ((x >> 16) & 1u)) >> 16;
  return (u16)r;
}
__device__ __forceinline__ float sigm(float x){ return 1.0f/(1.0f+expf(-x)); }

__device__ __forceinline__ void gload16(const u16* g, u16* l){
  __builtin_amdgcn_global_load_lds(
      (const __attribute__((address_space(1))) void*)g,
      (__attribute__((address_space(3))) void*)l, 16, 0, 0);
}

// ---------------------------------------------------------------------------
// Kernel 1: h0 = init_h[0] @ Wh^T + bh ; c0 = init_c[0] @ Wc^T + bc   (f32)
// Also zeroes the 32 scan barrier flags (padded 64B apart) every call.
// ---------------------------------------------------------------------------
__global__ __launch_bounds__(256) void k_init(
    const float* __restrict__ init_h, const float* __restrict__ init_c,
    const float* __restrict__ Wh, const float* __restrict__ bh,
    const float* __restrict__ Wc, const float* __restrict__ bc,
    float* __restrict__ h0out, float* __restrict__ c0out,
    unsigned int* __restrict__ flag)
{
  if (blockIdx.x == 0){ flag[threadIdx.x] = 0u; flag[threadIdx.x + 256] = 0u; }
  int idx = blockIdx.x*blockDim.x + threadIdx.x;    // 0..32767
  int sel = idx >> 14;                              // 0: h, 1: c
  int r = idx & 16383;
  int b = r >> 9, j = r & 511;
  const float* x = (sel ? init_c : init_h) + b*H_;
  const float* w = (sel ? Wc : Wh) + (size_t)j*H_;
  const float* bias = sel ? bc : bh;
  float acc = 0.f;
  for (int k = 0; k < H_; k += 8){
    f32x4 x0 = *(const f32x4*)(x + k), x1 = *(const f32x4*)(x + k + 4);
    f32x4 w0 = *(const f32x4*)(w + k), w1 = *(const f32x4*)(w + k + 4);
    acc += x0[0]*w0[0] + x0[1]*w0[1] + x0[2]*w0[2] + x0[3]*w0[3];
    acc += x1[0]*w1[0] + x1[1]*w1[1] + x1[2]*w1[2] + x1[3]*w1[3];
  }
  acc += bias[j];
  (sel ? c0out : h0out)[b*H_ + j] = acc;
}

// ---------------------------------------------------------------------------
// Kernel 2 (merged): blocks [0,256): xg GEMM (M=2048,N=2048,K=300, tokens
// gathered from embedding). blocks [256,8256): W_logit f32->bf16 cvt
// (8 elems/thread) -- hidden under the xgates tail instead of a serial launch.
// ---------------------------------------------------------------------------
__global__ __launch_bounds__(256) void k_xgates(
    const float* __restrict__ emb, const float* __restrict__ Wih,
    const int* __restrict__ trg, const float* __restrict__ bih,
    const float* __restrict__ bhh, float* __restrict__ xg,
    const float* __restrict__ Wlogit, u16* __restrict__ W16)
{
  const int bid = blockIdx.x;
  const int tid = threadIdx.x;
  if (bid >= 256){
    size_t i = ((size_t)(bid - 256)*256 + tid)*8;
    f32x4 a = *(const f32x4*)(Wlogit + i);
    f32x4 b = *(const f32x4*)(Wlogit + i + 4);
    us8 u;
    u[0]=f2b(a[0]); u[1]=f2b(a[1]); u[2]=f2b(a[2]); u[3]=f2b(a[3]);
    u[4]=f2b(b[0]); u[5]=f2b(b[1]); u[6]=f2b(b[2]); u[7]=f2b(b[3]);
    *(us8*)(W16 + i) = u;
    return;
  }
  __shared__ u16 As[128][40];   // +8 pad: row stride 80B -> conflict-free b128
  __shared__ u16 Bs[128][40];
  const int bn0 = (bid & 15)*128, bm0 = (bid >> 4)*128;
  const int w = tid>>6, lane = tid&63;
  const int wr = w>>1, wc = w&1, lr = lane&15, lk = lane>>4;
  const int srow = tid>>1, half = tid&1;
  const int R = bm0 + srow;
  const int tt = R>>5, bb = R&31;
  const int token = trg[bb*T_ + tt];
  const float* arow = emb + (size_t)token*E_;
  const float* brow = Wih + (size_t)(bn0+srow)*E_;
  f32x4 acc[4][4] = {};
  for (int k0 = 0; k0 < E_; k0 += 32){
    int cbase = k0 + half*16;
    if (k0 + 32 <= E_){
      f32x4 a0=*(const f32x4*)(arow+cbase),    a1=*(const f32x4*)(arow+cbase+4);
      f32x4 a2=*(const f32x4*)(arow+cbase+8),  a3=*(const f32x4*)(arow+cbase+12);
      f32x4 b0=*(const f32x4*)(brow+cbase),    b1=*(const f32x4*)(brow+cbase+4);
      f32x4 b2=*(const f32x4*)(brow+cbase+8),  b3=*(const f32x4*)(brow+cbase+12);
      us8 ua, ub;
      ua[0]=f2b(a0[0]); ua[1]=f2b(a0[1]); ua[2]=f2b(a0[2]); ua[3]=f2b(a0[3]);
      ua[4]=f2b(a1[0]); ua[5]=f2b(a1[1]); ua[6]=f2b(a1[2]); ua[7]=f2b(a1[3]);
      ub[0]=f2b(a2[0]); ub[1]=f2b(a2[1]); ub[2]=f2b(a2[2]); ub[3]=f2b(a2[3]);
      ub[4]=f2b(a3[0]); ub[5]=f2b(a3[1]); ub[6]=f2b(a3[2]); ub[7]=f2b(a3[3]);
      *(us8*)&As[srow][half*16]   = ua;
      *(us8*)&As[srow][half*16+8] = ub;
      us8 va, vb;
      va[0]=f2b(b0[0]); va[1]=f2b(b0[1]); va[2]=f2b(b0[2]); va[3]=f2b(b0[3]);
      va[4]=f2b(b1[0]); va[5]=f2b(b1[1]); va[6]=f2b(b1[2]); va[7]=f2b(b1[3]);
      vb[0]=f2b(b2[0]); vb[1]=f2b(b2[1]); vb[2]=f2b(b2[2]); vb[3]=f2b(b2[3]);
      vb[4]=f2b(b3[0]); vb[5]=f2b(b3[1]); vb[6]=f2b(b3[2]); vb[7]=f2b(b3[3]);
      *(us8*)&Bs[srow][half*16]   = va;
      *(us8*)&Bs[srow][half*16+8] = vb;
    } else {
      for (int i = 0; i < 16; i++){
        int c = cbase + i;
        As[srow][half*16+i] = (c < E_) ? f2b(arow[c]) : (u16)0;
        Bs[srow][half*16+i] = (c < E_) ? f2b(brow[c]) : (u16)0;
      }
    }
    __syncthreads();
    bf16x8 af[4], bfr[4];
    #pragma unroll
    for (int m = 0; m < 4; m++) af[m] = *(const bf16x8*)&As[wr*64 + m*16 + lr][lk*8];
    #pragma unroll
    for (int n = 0; n < 4; n++) bfr[n] = *(const bf16x8*)&Bs[wc*64 + n*16 + lr][lk*8];
    #pragma unroll
    for (int m = 0; m < 4; m++)
      #pragma unroll
      for (int n = 0; n < 4; n++)
        acc[m][n] = __builtin_amdgcn_mfma_f32_16x16x32_bf16(af[m], bfr[n], acc[m][n], 0, 0, 0);
    __syncthreads();
  }
  #pragma unroll
  for (int n = 0; n < 4; n++){
    int col = bn0 + wc*64 + n*16 + lr;
    float bv = bih[col] + bhh[col];
    #pragma unroll
    for (int m = 0; m < 4; m++){
      #pragma unroll
      for (int i = 0; i < 4; i++){
        int row = bm0 + wr*64 + m*16 + lk*4 + i;
        xg[(size_t)row*G4_ + col] = acc[m][n][i] + bv;
      }
    }
  }
}

// ---------------------------------------------------------------------------
// Mega kernel (cooperative, 256 blocks x 512 thr). R20 structure; worker
// tile walk reordered into mt-PAIRS sharing one nt: tile (2*mt2,nt) then
// (2*mt2+1,nt) back-to-back, so the second tile's W panel (131 KB, just
// loaded) hits L2 -> raw W HBM traffic halves (R20 FETCH 294MB, W-driven).
// Gates stay per-mt (want=4mt+5, non-decreasing along the walk).
//   blocks [0,32):   LSTM scan (round-9 structure) + final release flag=65.
//   blocks [32,256): persistent logits GEMM, BK=64 (8 k-iters/tile).
// LDS: manual union, 41472 B (scan: 33280+8192; gemm: 2x16384).
// ---------------------------------------------------------------------------
__global__ __launch_bounds__(512) void k_mega(
    const float* __restrict__ Whh, const float* __restrict__ xg,
    const float* __restrict__ h0, const float* __restrict__ c0,
    u16* __restrict__ h_g, u16* __restrict__ A_buf,
    unsigned int* __restrict__ flag,
    const u16* __restrict__ W16, const float* __restrict__ bias,
    float* __restrict__ out)
{
  __shared__ __align__(16) char smem[41472];
  const int tid = threadIdx.x;

  if (blockIdx.x < NBLK_){
    // ======================= SCAN PATH (round-9 verbatim) ==================
    u16 (*hl)[520] = (u16(*)[520])smem;
    float (*gb)[32][16] = (float(*)[32][16])(smem + 33280);
    const int bj = blockIdx.x;
    const int wv = tid >> 6, lane = tid & 63;
    const int g = wv >> 1, m = wv & 1;
    const int lr = lane & 15, lk = lane >> 4;

    bf16x8 bw[16];
    {
      const float* wsrc = Whh + (size_t)(g*H_ + bj*16 + lr)*H_;
      #pragma unroll
      for (int ks = 0; ks < 16; ks++){
        f32x4 w0 = *(const f32x4*)(wsrc + ks*32 + lk*8);
        f32x4 w1 = *(const f32x4*)(wsrc + ks*32 + lk*8 + 4);
        us8 u;
        u[0]=f2b(w0[0]); u[1]=f2b(w0[1]); u[2]=f2b(w0[2]); u[3]=f2b(w0[3]);
        u[4]=f2b(w1[0]); u[5]=f2b(w1[1]); u[6]=f2b(w1[2]); u[7]=f2b(w1[3]);
        bw[ks] = __builtin_bit_cast(bf16x8, u);
      }
    }
    const int ub = tid >> 4, uj = tid & 15;
    float c_reg = c0[ub*H_ + bj*16 + uj];

    {
      int r = tid >> 4, seg = tid & 15;
      const float* src = h0 + r*H_ + seg*32;
      #pragma unroll
      for (int q = 0; q < 4; q++){
        f32x4 v0 = *(const f32x4*)(src + q*8);
        f32x4 v1 = *(const f32x4*)(src + q*8 + 4);
        us8 u;
        u[0]=f2b(v0[0]); u[1]=f2b(v0[1]); u[2]=f2b(v0[2]); u[3]=f2b(v0[3]);
        u[4]=f2b(v1[0]); u[5]=f2b(v1[1]); u[6]=f2b(v1[2]); u[7]=f2b(v1[3]);
        *(us8*)&hl[r][seg*32 + q*8] = u;
      }
    }
    __syncthreads();

    for (int t = 0; t < T_; t++){
      const float* xr = xg + (size_t)t*(B_*G4_) + ub*G4_ + bj*16 + uj;
      float x0 = xr[0*H_], x1 = xr[1*H_], x2 = xr[2*H_], x3 = xr[3*H_];

      f32x4 acc = {0.f, 0.f, 0.f, 0.f};
      #pragma unroll
      for (int ks = 0; ks < 16; ks++){
        bf16x8 a = *(const bf16x8*)&hl[m*16 + lr][ks*32 + lk*8];
        acc = __builtin_amdgcn_mfma_f32_16x16x32_bf16(a, bw[ks], acc, 0, 0, 0);
      }
      #pragma unroll
      for (int i = 0; i < 4; i++)
        gb[g][m*16 + lk*4 + i][lr] = acc[i];
      __syncthreads();

      float gi = sigm(gb[0][ub][uj] + x0);
      float gf = sigm(gb[1][ub][uj] + x1);
      float gg = tanhf(gb[2][ub][uj] + x2);
      float go = sigm(gb[3][ub][uj] + x3);
      c_reg = gf*c_reg + gi*gg;
      float h = go * tanhf(c_reg);
      int p = (t+1) & 1;
      h_g[p*(B_*H_) + bj*(B_*16) + tid] = f2b(h);

      __syncthreads();   // drains h_g stores (vmcnt0) before release
      if (t < T_-1 && tid == 0)
        __hip_atomic_store(&flag[bj*16], (unsigned)(t+1),
                           __ATOMIC_RELEASE, __HIP_MEMORY_SCOPE_AGENT);

      A_buf[(size_t)t*(B_*H_) + ub*H_ + bj*16 + uj] = f2b(tanhf(h));
      if (t == T_-1) break;

      if (tid < 64){
        unsigned want = (unsigned)(t+1), guard = 0;
        while (__hip_atomic_load(&flag[(tid&31)*16], __ATOMIC_ACQUIRE,
                                 __HIP_MEMORY_SCOPE_AGENT) < want
               && guard < (1u<<18)) { __builtin_amdgcn_s_sleep(1); ++guard; }
      }
      __syncthreads();

      {
        int r = tid >> 4, seg = tid & 15;
        const u16* hb = h_g + p*(B_*H_);
        const u16* p0 = hb + (seg*2)  *(B_*16) + r*16;
        const u16* p1 = hb + (seg*2+1)*(B_*16) + r*16;
        us8 v0 = *(const us8*)(p0);
        us8 v1 = *(const us8*)(p0 + 8);
        us8 v2 = *(const us8*)(p1);
        us8 v3 = *(const us8*)(p1 + 8);
        *(us8*)&hl[r][seg*32]      = v0;
        *(us8*)&hl[r][seg*32 + 8]  = v1;
        *(us8*)&hl[r][seg*32 + 16] = v2;
        *(us8*)&hl[r][seg*32 + 24] = v3;
      }
      __syncthreads();
    }
    // final publish: A of t=63 (and all prior) flushed by this release
    __syncthreads();   // drain last A_buf stores
    if (tid == 0)
      __hip_atomic_store(&flag[bj*16], 65u,
                         __ATOMIC_RELEASE, __HIP_MEMORY_SCOPE_AGENT);
  } else {
    // ======== GEMM PATH (BK=64, mt-pairs sharing nt for W L2 reuse) =======
    u16* As = (u16*)smem;             // [128][64] u16, 16 KB
    u16* Bs = (u16*)(smem + 16384);   // [128][64] u16, 16 KB
    const int w = tid>>6, lane = tid&63;
    const int wr = w & 1, wc = w >> 1;               // 2 x 4 wave grid
    const int lr = lane&15, lk = lane>>4;
    const int r0 = w*8 + (lane>>3);                  // rows for instr 0
    const int r1 = 64 + r0;                          // rows for instr 1
    const int c0b = ((lane&7)*16) ^ ((r0&7)<<4);     // swizzled byte-col
    const int c1b = ((lane&7)*16) ^ ((r1&7)<<4);
    u16* adst0 = &As[(w*8)*64];
    u16* adst1 = &As[(64 + w*8)*64];
    u16* bdst0 = &Bs[(w*8)*64];
    u16* bdst1 = &Bs[(64 + w*8)*64];

    int prev_want = -1;
    for (int pt = (int)blockIdx.x - NBLK_; pt < 8*NT_TILES; pt += NG_){
      const int mt2 = pt / NT_TILES;      // 0..7, non-decreasing per block
      const int nt  = pt - mt2*NT_TILES;  // 0..249
      const int bn0 = nt*128;
      const u16* b0p = W16 + (size_t)(bn0+r0)*H_ + (c0b>>1);
      const u16* b1p = W16 + (size_t)(bn0+r1)*H_ + (c1b>>1);
      #pragma unroll
      for (int hh = 0; hh < 2; hh++){
        const int mt = 2*mt2 + hh;
        const int bm0 = mt*128;
        const unsigned want = (mt < 15) ? (unsigned)(4*mt + 5) : 65u;
        if ((int)want != prev_want){
          if (tid < 64){
            unsigned guard = 0;
            for (;;){
              unsigned v = __hip_atomic_load(&flag[(tid&31)*16], __ATOMIC_RELAXED,
                                             __HIP_MEMORY_SCOPE_AGENT);
              if (__all(v >= want) || guard > (1u<<20)) break;
              __builtin_amdgcn_s_sleep(8); ++guard;
            }
            __builtin_amdgcn_fence(__ATOMIC_ACQUIRE, "agent");  // one inv/gate
          }
          prev_want = (int)want;
        }
        __syncthreads();   // wait visible to all + LDS free

        const u16* a0p = A_buf + (size_t)(bm0+r0)*H_ + (c0b>>1);
        const u16* a1p = A_buf + (size_t)(bm0+r1)*H_ + (c1b>>1);
        f32x4 acc[4][2] = {};
        for (int k0 = 0; k0 < H_; k0 += 64){
          gload16(a0p + k0, adst0);
          gload16(a1p + k0, adst1);
          gload16(b0p + k0, bdst0);
          gload16(b1p + k0, bdst1);
          __syncthreads();
          #pragma unroll
          for (int s = 0; s < 2; s++){
            bf16x8 af[4], bfr[2];
            #pragma unroll
            for (int m = 0; m < 4; m++){
              int row = wr*64 + m*16 + lr;
              af[m] = *(const bf16x8*)((const char*)As + row*128
                         + ((s*64 + lk*16) ^ ((row&7)<<4)));
            }
            #pragma unroll
            for (int n = 0; n < 2; n++){
              int row = wc*32 + n*16 + lr;
              bfr[n] = *(const bf16x8*)((const char*)Bs + row*128
                         + ((s*64 + lk*16) ^ ((row&7)<<4)));
            }
            #pragma unroll
            for (int m = 0; m < 4; m++)
              #pragma unroll
              for (int n = 0; n < 2; n++)
                acc[m][n] = __builtin_amdgcn_mfma_f32_16x16x32_bf16(af[m], bfr[n], acc[m][n], 0, 0, 0);
          }
          __syncthreads();
        }
        #pragma unroll
        for (int n = 0; n < 2; n++){
          int col = bn0 + wc*32 + n*16 + lr;
          float bv = bias[col];
          #pragma unroll
          for (int m = 0; m < 4; m++){
            #pragma unroll
            for (int i = 0; i < 4; i++){
              int row = bm0 + wr*64 + m*16 + lk*4 + i;
              int t = row>>5, b = row&31;
              __builtin_nontemporal_store(acc[m][n][i] + bv,
                  &out[(size_t)b*((size_t)T_*V_) + (size_t)t*V_ + col]);
            }
          }
        }
      }
    }
  }
}

// ---------------------------------------------------------------------------
// Standalone fallback kernels (round-9 proven, 499us total path).
// ---------------------------------------------------------------------------
__global__ __launch_bounds__(512) void k_scan(
    const float* __restrict__ Whh, const float* __restrict__ xg,
    const float* __restrict__ h0, const float* __restrict__ c0,
    u16* __restrict__ h_g, u16* __restrict__ A_buf,
    unsigned int* __restrict__ flag)
{
  __shared__ u16 hl[32][520];
  __shared__ float gb[4][32][16];
  const int bj = blockIdx.x;
  const int tid = threadIdx.x;
  const int wv = tid >> 6, lane = tid & 63;
  const int g = wv >> 1, m = wv & 1;
  const int lr = lane & 15, lk = lane >> 4;
  bf16x8 bw[16];
  {
    const float* wsrc = Whh + (size_t)(g*H_ + bj*16 + lr)*H_;
    #pragma unroll
    for (int ks = 0; ks < 16; ks++){
      f32x4 w0 = *(const f32x4*)(wsrc + ks*32 + lk*8);
      f32x4 w1 = *(const f32x4*)(wsrc + ks*32 + lk*8 + 4);
      us8 u;
      u[0]=f2b(w0[0]); u[1]=f2b(w0[1]); u[2]=f2b(w0[2]); u[3]=f2b(w0[3]);
      u[4]=f2b(w1[0]); u[5]=f2b(w1[1]); u[6]=f2b(w1[2]); u[7]=f2b(w1[3]);
      bw[ks] = __builtin_bit_cast(bf16x8, u);
    }
  }
  const int ub = tid >> 4, uj = tid & 15;
  float c_reg = c0[ub*H_ + bj*16 + uj];
  {
    int r = tid >> 4, seg = tid & 15;
    const float* src = h0 + r*H_ + seg*32;
    #pragma unroll
    for (int q = 0; q < 4; q++){
      f32x4 v0 = *(const f32x4*)(src + q*8);
      f32x4 v1 = *(const f32x4*)(src + q*8 + 4);
      us8 u;
      u[0]=f2b(v0[0]); u[1]=f2b(v0[1]); u[2]=f2b(v0[2]); u[3]=f2b(v0[3]);
      u[4]=f2b(v1[0]); u[5]=f2b(v1[1]); u[6]=f2b(v1[2]); u[7]=f2b(v1[3]);
      *(us8*)&hl[r][seg*32 + q*8] = u;
    }
  }
  __syncthreads();
  for (int t = 0; t < T_; t++){
    const float* xr = xg + (size_t)t*(B_*G4_) + ub*G4_ + bj*16 + uj;
    float x0 = xr[0*H_], x1 = xr[1*H_], x2 = xr[2*H_], x3 = xr[3*H_];
    f32x4 acc = {0.f, 0.f, 0.f, 0.f};
    #pragma unroll
    for (int ks = 0; ks < 16; ks++){
      bf16x8 a = *(const bf16x8*)&hl[m*16 + lr][ks*32 + lk*8];
      acc = __builtin_amdgcn_mfma_f32_16x16x32_bf16(a, bw[ks], acc, 0, 0, 0);
    }
    #pragma unroll
    for (int i = 0; i < 4; i++)
      gb[g][m*16 + lk*4 + i][lr] = acc[i];
    __syncthreads();
    float gi = sigm(gb[0][ub][uj] + x0);
    float gf = sigm(gb[1][ub][uj] + x1);
    float gg = tanhf(gb[2][ub][uj] + x2);
    float go = sigm(gb[3][ub][uj] + x3);
    c_reg = gf*c_reg + gi*gg;
    float h = go * tanhf(c_reg);
    int p = (t+1) & 1;
    h_g[p*(B_*H_) + bj*(B_*16) + tid] = f2b(h);
    __syncthreads();
    if (t < T_-1 && tid == 0)
      __hip_atomic_store(&flag[bj*16], (unsigned)(t+1),
                         __ATOMIC_RELEASE, __HIP_MEMORY_SCOPE_AGENT);
    A_buf[(size_t)t*(B_*H_) + ub*H_ + bj*16 + uj] = f2b(tanhf(h));
    if (t == T_-1) break;
    if (tid < 64){
      unsigned want = (unsigned)(t+1), guard = 0;
      while (__hip_atomic_load(&flag[(tid&31)*16], __ATOMIC_ACQUIRE,
                               __HIP_MEMORY_SCOPE_AGENT) < want
             && guard < (1u<<18)) { __builtin_amdgcn_s_sleep(1); ++guard; }
    }
    __syncthreads();
    {
      int r = tid >> 4, seg = tid & 15;
      const u16* hb = h_g + p*(B_*H_);
      const u16* p0 = hb + (seg*2)  *(B_*16) + r*16;
      const u16* p1 = hb + (seg*2+1)*(B_*16) + r*16;
      us8 v0 = *(const us8*)(p0);
      us8 v1 = *(const us8*)(p0 + 8);
      us8 v2 = *(const us8*)(p1);
      us8 v3 = *(const us8*)(p1 + 8);
      *(us8*)&hl[r][seg*32]      = v0;
      *(us8*)&hl[r][seg*32 + 8]  = v1;
      *(us8*)&hl[r][seg*32 + 16] = v2;
      *(us8*)&hl[r][seg*32 + 24] = v3;
    }
    __syncthreads();
  }
}

__global__ __launch_bounds__(256) void k_logits16(
    const u16* __restrict__ A, const u16* __restrict__ W16,
    const float* __restrict__ bias, float* __restrict__ out)
{
  __shared__ u16 As[128*32];
  __shared__ u16 Bs[128*32];
  int bid = blockIdx.y*16 + blockIdx.x;      // 0..3999
  int nbid = (bid & 7)*500 + (bid >> 3);     // bijective (4000 = 8*500)
  const int bm0 = (nbid & 15)*128;
  const int bn0 = (nbid >> 4)*128;
  const int tid = threadIdx.x;
  const int w = tid>>6, lane = tid&63;
  const int wr = w>>1, wc = w&1, lr = lane&15, lk = lane>>4;
  const int srow = w*32 + (lane>>2);
  const int cb   = ((lane&3)*16) ^ (((srow>>1)&3)<<4);
  const u16* aptr = A   + (size_t)(bm0+srow)*H_ + (cb>>1);
  const u16* bptr = W16 + (size_t)(bn0+srow)*H_ + (cb>>1);
  u16* adst0 = &As[(w*32)*32];
  u16* adst1 = &As[(w*32+16)*32];
  u16* bdst0 = &Bs[(w*32)*32];
  u16* bdst1 = &Bs[(w*32+16)*32];
  f32x4 acc[4][4] = {};
  for (int k0 = 0; k0 < H_; k0 += 32){
    gload16(aptr + k0,          adst0);
    gload16(aptr + k0 + 16*H_,  adst1);
    gload16(bptr + k0,          bdst0);
    gload16(bptr + k0 + 16*H_,  bdst1);
    __syncthreads();
    bf16x8 af[4], bfr[4];
    #pragma unroll
    for (int m = 0; m < 4; m++){
      int row = wr*64 + m*16 + lr;
      af[m] = *(const bf16x8*)((const char*)As + row*64 + ((lk*16) ^ (((row>>1)&3)<<4)));
    }
    #pragma unroll
    for (int n = 0; n < 4; n++){
      int row = wc*64 + n*16 + lr;
      bfr[n] = *(const bf16x8*)((const char*)Bs + row*64 + ((lk*16) ^ (((row>>1)&3)<<4)));
    }
    #pragma unroll
    for (int m = 0; m < 4; m++)
      #pragma unroll
      for (int n = 0; n < 4; n++)
        acc[m][n] = __builtin_amdgcn_mfma_f32_16x16x32_bf16(af[m], bfr[n], acc[m][n], 0, 0, 0);
    __syncthreads();
  }
  #pragma unroll
  for (int n = 0; n < 4; n++){
    int col = bn0 + wc*64 + n*16 + lr;
    float bv = bias[col];
    #pragma unroll
    for (int m = 0; m < 4; m++){
      #pragma unroll
      for (int i = 0; i < 4; i++){
        int row = bm0 + wr*64 + m*16 + lk*4 + i;
        int t = row>>5, b = row&31;
        __builtin_nontemporal_store(acc[m][n][i] + bv,
            &out[(size_t)b*((size_t)T_*V_) + (size_t)t*V_ + col]);
      }
    }
  }
}

__global__ __launch_bounds__(256) void k_logits(
    const u16* __restrict__ A, const float* __restrict__ W,
    const float* __restrict__ bias, float* __restrict__ out)
{
  __shared__ u16 As[128][40];
  __shared__ u16 Bs[128][40];
  const int bm0 = blockIdx.x*128, bn0 = blockIdx.y*128;
  const int tid = threadIdx.x;
  const int w = tid>>6, lane = tid&63;
  const int wr = w>>1, wc = w&1, lr = lane&15, lk = lane>>4;
  const int srow = tid>>1, half = tid&1;
  const u16*   arow = A + (size_t)(bm0+srow)*H_;
  const float* brow = W + (size_t)(bn0+srow)*H_;
  f32x4 acc[4][4] = {};
  for (int k0 = 0; k0 < H_; k0 += 32){
    us8 a0 = *(const us8*)(arow + k0 + half*16);
    us8 a1 = *(const us8*)(arow + k0 + half*16 + 8);
    f32x4 b0 = *(const f32x4*)(brow + k0 + half*16);
    f32x4 b1 = *(const f32x4*)(brow + k0 + half*16 + 4);
    f32x4 b2 = *(const f32x4*)(brow + k0 + half*16 + 8);
    f32x4 b3 = *(const f32x4*)(brow + k0 + half*16 + 12);
    *(us8*)&As[srow][half*16]   = a0;
    *(us8*)&As[srow][half*16+8] = a1;
    us8 vb0, vb1;
    vb0[0]=f2b(b0[0]); vb0[1]=f2b(b0[1]); vb0[2]=f2b(b0[2]); vb0[3]=f2b(b0[3]);
    vb0[4]=f2b(b1[0]); vb0[5]=f2b(b1[1]); vb0[6]=f2b(b1[2]); vb0[7]=f2b(b1[3]);
    vb1[0]=f2b(b2[0]); vb1[1]=f2b(b2[1]); vb1[2]=f2b(b2[2]); vb1[3]=f2b(b2[3]);
    vb1[4]=f2b(b3[0]); vb1[5]=f2b(b3[1]); vb1[6]=f2b(b3[2]); vb1[7]=f2b(b3[3]);
    *(us8*)&Bs[srow][half*16]   = vb0;
    *(us8*)&Bs[srow][half*16+8] = vb1;
    __syncthreads();
    bf16x8 af[4], bfr[4];
    #pragma unroll
    for (int m = 0; m < 4; m++) af[m] = *(const bf16x8*)&As[wr*64 + m*16 + lr][lk*8];
    #pragma unroll
    for (int n = 0; n < 4; n++) bfr[n] = *(const bf16x8*)&Bs[wc*64 + n*16 + lr][lk*8];
    #pragma unroll
    for (int m = 0; m < 4; m++)
      #pragma unroll
      for (int n = 0; n < 4; n++)
        acc[m][n] = __builtin_amdgcn_mfma_f32_16x16x32_bf16(af[m], bfr[n], acc[m][n], 0, 0, 0);
    __syncthreads();
  }
  #pragma unroll
  for (int n = 0; n < 4; n++){
    int col = bn0 + wc*64 + n*16 + lr;
    float bv = bias[col];
    #pragma unroll
    for (int m = 0; m < 4; m++){
      #pragma unroll
      for (int i = 0; i < 4; i++){
        int row = bm0 + wr*64 + m*16 + lk*4 + i;
        int t = row>>5, b = row&31;
        out[(size_t)b*((size_t)T_*V_) + (size_t)t*V_ + col] = acc[m][n][i] + bv;
      }
    }
  }
}

// ---------------------------------------------------------------------------
extern "C" void kernel_launch(void* const* d_in, const int* in_sizes, int n_in,
                              void* d_out, int out_size, void* d_ws, size_t ws_size,
                              hipStream_t stream)
{
  const int*   trg    = (const int*)d_in[0];
  const float* init_h = (const float*)d_in[1];
  const float* init_c = (const float*)d_in[2];
  const float* emb    = (const float*)d_in[3];
  const float* Wh     = (const float*)d_in[4];
  const float* bh     = (const float*)d_in[5];
  const float* Wc     = (const float*)d_in[6];
  const float* bc     = (const float*)d_in[7];
  const float* Wih    = (const float*)d_in[8];
  const float* Whh    = (const float*)d_in[9];
  const float* bih    = (const float*)d_in[10];
  const float* bhh    = (const float*)d_in[11];
  const float* Wlogit = (const float*)d_in[12];
  const float* blogit = (const float*)d_in[13];
  float* out = (float*)d_out;

  // workspace layout (bytes)
  char* ws = (char*)d_ws;
  float*        xg    = (float*)(ws);               // 16,777,216
  float*        h0    = (float*)(ws + 16777216);    //     65,536
  float*        c0    = (float*)(ws + 16842752);    //     65,536
  u16*          A_buf = (u16*)  (ws + 16908288);    //  2,097,152
  u16*          h_g   = (u16*)  (ws + 19005440);    //    131,072 (2 parities)
  unsigned int* flag  = (unsigned int*)(ws + 19136512); // 2,048 (32 x 64B)
  u16*          W16   = (u16*)  (ws + 19138560);    // 32,768,000 (optional)
  const size_t need_w16 = 19138560ull + 32768000ull;
  const bool use_w16 = (ws_size >= need_w16);

  hipLaunchKernelGGL(k_init, dim3(128), dim3(256), 0, stream,
                     init_h, init_c, Wh, bh, Wc, bc, h0, c0, flag);
  // merged xgates + (optional) W16 cvt: cvt blocks hide under xgates tail
  hipLaunchKernelGGL(k_xgates, dim3(use_w16 ? 8256 : 256), dim3(256), 0, stream,
                     emb, Wih, trg, bih, bhh, xg, Wlogit, W16);
  if (use_w16){
    void* args[] = { (void*)&Whh, (void*)&xg, (void*)&h0, (void*)&c0,
                     (void*)&h_g, (void*)&A_buf, (void*)&flag,
                     (void*)&W16, (void*)&blogit, (void*)&out };
    hipError_t merr = hipLaunchCooperativeKernel((void*)k_mega,
                          dim3(NBLK_ + NG_), dim3(512), args, 0, stream);
    if (merr != hipSuccess){
      // fallback: proven round-9 pipeline (deterministic: capacity is static)
      void* sargs[] = { (void*)&Whh, (void*)&xg, (void*)&h0, (void*)&c0,
                        (void*)&h_g, (void*)&A_buf, (void*)&flag };
      hipLaunchCooperativeKernel((void*)k_scan, dim3(NBLK_), dim3(512),
                                 sargs, 0, stream);
      hipLaunchKernelGGL(k_logits16, dim3(16, 250), dim3(256), 0, stream,
                         A_buf, W16, blogit, out);
    }
  } else {
    void* args[] = { (void*)&Whh, (void*)&xg, (void*)&h0, (void*)&c0,
                     (void*)&h_g, (void*)&A_buf, (void*)&flag };
    hipLaunchCooperativeKernel((void*)k_scan, dim3(NBLK_), dim3(512), args, 0, stream);
    hipLaunchKernelGGL(k_logits, dim3(16, 250), dim3(256), 0, stream,
                       A_buf, Wlogit, blogit, out);
  }
}